// Round 21
// baseline (529.282 us; speedup 1.0000x reference)
//
#include <hip/hip_runtime.h>
#include <math.h>

// twoB=8, L=4096 (H=W=64), C=256, d_inner=512, nh_m=8, hd=64, D_STATE=64,
// conv_dim=640, zx width=1160, CHUNK=256 (16 chunks/batch), WS=8, SS=4, NH=8, Dh=32.
// XC2: [tok][128] = B(64) || C(64).  XT: [g][ch<512][s] transposed conv-x.

#define DEVI static __device__ __forceinline__
typedef unsigned short u16;
typedef unsigned int   u32;
typedef __attribute__((ext_vector_type(8))) short s16x8;
typedef __attribute__((ext_vector_type(4))) float f32x4;

DEVI float sigm_(float x){ return 1.f/(1.f+__expf(-x)); }
DEVI float silu_(float x){ return x/(1.f+__expf(-x)); }
// tanh-form GELU via sigmoid identity: 0.5x(1+tanh(y)) == x*sigmoid(2y),
// 2y = 1.5957691216x + 0.0713548162x^3.  |err vs exact| ~3e-4.
DEVI float gelu_(float x){
  return x * sigm_(x*(1.5957691216f + 0.0713548162f*x*x));
}
DEVI float wsum_(float v){
#pragma unroll
  for (int o=32;o>0;o>>=1) v += __shfl_xor(v,o,64);
  return v;
}

DEVI float b2f(u16 u){ union{u32 i; float f;} v; v.i = ((u32)u)<<16; return v.f; }
DEVI u16 f2b(float f){ union{float f; u32 i;} v; v.f=f; u32 r = v.i + 0x7fffu + ((v.i>>16)&1u); return (u16)(r>>16); }
DEVI float4 ld4(const float* p){ return *(const float4*)p; }
DEVI float4 ld4(const u16* p){
  uint2 r = *(const uint2*)p;
  return make_float4(b2f((u16)(r.x&0xffff)), b2f((u16)(r.x>>16)),
                     b2f((u16)(r.y&0xffff)), b2f((u16)(r.y>>16)));
}
DEVI void st4(u16* p, float a, float b, float c, float d){
  uint2 r; r.x = (u32)f2b(a) | ((u32)f2b(b)<<16); r.y = (u32)f2b(c) | ((u32)f2b(d)<<16);
  *(uint2*)p = r;
}
DEVI void ld8(const u16* p, float* f){
  uint4 r = *(const uint4*)p;
  f[0]=b2f((u16)(r.x&0xffff)); f[1]=b2f((u16)(r.x>>16));
  f[2]=b2f((u16)(r.y&0xffff)); f[3]=b2f((u16)(r.y>>16));
  f[4]=b2f((u16)(r.z&0xffff)); f[5]=b2f((u16)(r.z>>16));
  f[6]=b2f((u16)(r.w&0xffff)); f[7]=b2f((u16)(r.w>>16));
}
DEVI void st8(u16* p, const float* f){
  uint4 r;
  r.x=(u32)f2b(f[0])|((u32)f2b(f[1])<<16); r.y=(u32)f2b(f[2])|((u32)f2b(f[3])<<16);
  r.z=(u32)f2b(f[4])|((u32)f2b(f[5])<<16); r.w=(u32)f2b(f[6])|((u32)f2b(f[7])<<16);
  *(uint4*)p = r;
}
DEVI float tof(float v){ return v; }
DEVI float tof(u16 v){ return b2f(v); }
DEVI void sto(float* p, float v){ *p = v; }
DEVI void sto(u16* p, float v){ *p = f2b(v); }

// swizzle: spread 16B chunks of a [64-row][64-col u16] transposed tile
DEVI int vswz(int row, int ch){ return ch ^ ((row&7) ^ ((row>>3)&7)); }

// async global->LDS, 16B per lane; lds base must be wave-uniform.
DEVI void gl16(const u16* g, u16* l){
  __builtin_amdgcn_global_load_lds(
      (const __attribute__((address_space(1))) u32*)g,
      (__attribute__((address_space(3))) u32*)l, 16, 0, 0);
}

// XCD-aware remap of a linear block id (bijective when nwg%8==0)
DEVI void xcdswz(int lin, int nwg, int gx, int& bx, int& by){
  if ((nwg & 7) == 0){
    int nl = (lin & 7)*(nwg >> 3) + (lin >> 3);
    bx = nl % gx; by = nl / gx;
  } else { bx = lin % gx; by = lin / gx; }
}

// window row -> token map (roll by -4, 8x8 windows over 64x64, per batch)
DEVI int winmap_tok(int r){
  int win = r>>6, tk = r&63;
  int b = win>>6, wid = win&63;
  int h2 = ((wid>>3)<<3) + (tk>>3);
  int w2 = ((wid&7)<<3) + (tk&7);
  int hh = (h2+4)&63, wwp = (w2+4)&63;
  return b*4096 + hh*64 + wwp;
}

// ---------------- fused LN(x)->xn, LN(xn)->xns (bf16 outs) -----------------
__global__ __launch_bounds__(256) void ln2x_k(
    const float* __restrict__ x, const float* __restrict__ w1, const float* __restrict__ b1,
    const float* __restrict__ w2, const float* __restrict__ b2,
    u16* __restrict__ xn, u16* __restrict__ xns)
{
  int tok = blockIdx.x*4 + (threadIdx.x>>6);
  int lane = threadIdx.x & 63;
  size_t base = (size_t)tok*256 + lane*4;
  float4 v = *(const float4*)(x + base);
  float mu = wsum_(v.x+v.y+v.z+v.w) * (1.f/256.f);
  float ax=v.x-mu, ay=v.y-mu, az=v.z-mu, aw=v.w-mu;
  float var = wsum_(ax*ax+ay*ay+az*az+aw*aw) * (1.f/256.f);
  float r = rsqrtf(var+1e-5f);
  float4 wv = *(const float4*)(w1+lane*4);
  float4 bv = *(const float4*)(b1+lane*4);
  float ox=ax*r*wv.x+bv.x, oy=ay*r*wv.y+bv.y, oz=az*r*wv.z+bv.z, ow=aw*r*wv.w+bv.w;
  st4(xn + base, ox, oy, oz, ow);
  float mu2 = wsum_(ox+oy+oz+ow)*(1.f/256.f);
  float bx=ox-mu2, by=oy-mu2, bz=oz-mu2, bw=ow-mu2;
  float var2 = wsum_(bx*bx+by*by+bz*bz+bw*bw)*(1.f/256.f);
  float r2 = rsqrtf(var2+1e-5f);
  float4 w2v = *(const float4*)(w2+lane*4);
  float4 b2v = *(const float4*)(b2+lane*4);
  st4(xns + base, bx*r2*w2v.x+b2v.x, by*r2*w2v.y+b2v.y, bz*r2*w2v.z+b2v.z, bw*r2*w2v.w+b2v.w);
}

// ---------------- generic LayerNorm (C=256), bf16 out ----------------------
template<typename IT>
__global__ __launch_bounds__(256) void ln_k(
    const IT* __restrict__ in, const float* __restrict__ w, const float* __restrict__ b,
    u16* __restrict__ outp)
{
  int tok = blockIdx.x*4 + (threadIdx.x>>6);
  int lane = threadIdx.x & 63;
  size_t base = (size_t)tok*256 + lane*4;
  float4 v = ld4(in + base);
  float mu = wsum_(v.x+v.y+v.z+v.w) * (1.f/256.f);
  float ax=v.x-mu, ay=v.y-mu, az=v.z-mu, aw=v.w-mu;
  float var = wsum_(ax*ax+ay*ay+az*az+aw*aw) * (1.f/256.f);
  float r = rsqrtf(var+1e-5f);
  float4 wv = *(const float4*)(w+lane*4);
  float4 bv = *(const float4*)(b+lane*4);
  st4(outp + base, ax*r*wv.x+bv.x, ay*r*wv.y+bv.y, az*r*wv.z+bv.z, aw*r*wv.w+bv.w);
}

// ------- ALL weight transposes in ONE launch: fp32[K][N](ldw) -> bf16[N][K] -
struct WtD { const float* W; u16* Wt; int ldw, K, kb, nt; };
struct WtTab { WtD d[15]; };

__global__ __launch_bounds__(256) void wtall_k(WtTab tab)
{
  int loc = blockIdx.x;
  int r = 0;
#pragma unroll
  for (int i=0;i<15;i++){
    int cnt = tab.d[i].kb * tab.d[i].nt;
    if (loc >= cnt && r == i){ loc -= cnt; r = i+1; }
  }
  const float* W = tab.d[r].W;
  u16* Wt = tab.d[r].Wt;
  int ldw = tab.d[r].ldw, K = tab.d[r].K, kb = tab.d[r].kb;
  int k0 = (loc % kb)*32, n0 = (loc / kb)*32;
  __shared__ float tl[32][33];
  int t = threadIdx.x; int ty=t>>5, tx=t&31;
#pragma unroll
  for (int i=0;i<4;i++){
    int k = ty + i*8;
    tl[k][tx] = W[(size_t)(k0+k)*ldw + n0+tx];
  }
  __syncthreads();
#pragma unroll
  for (int i=0;i<4;i++){
    int n = ty + i*8;
    Wt[(size_t)(n0+n)*K + k0 + tx] = f2b(tl[tx][n]);
  }
}

enum { EPI_NONE=0, EPI_SILU=1, EPI_GELU=2, EPI_SIGMUL=3, EPI_ADD=4, EPI_RELU=5, EPI_SIGMOID=6 };

// -------- MFMA GEMM: out[M,N] = epi(cat(A1,A2)[M,K] @ Wt[N,K]^T + bias) ----
// XCD-aware block swizzle: blocks sharing an A-panel land on one XCD's L2.
template<int BM, int BN, int EPI, bool WIN, bool WINST, typename OT, typename CT>
__global__ __launch_bounds__(256) void mgemm_k(
    const u16* __restrict__ A1, const u16* __restrict__ A2, int K1, int K2,
    const u16* __restrict__ Wt, const float* __restrict__ bias,
    const OT* other, CT* outp, int N, int r0)
{
  constexpr int MW = BM/32;
  constexpr int NWF = BN/32;
  constexpr int LA = BM/32;
  constexpr int LB = BN/32;
  __shared__ u16 As[BM][64];
  __shared__ u16 Bs[BN][64];
  int bx, by;
  xcdswz(blockIdx.y*gridDim.x + blockIdx.x, gridDim.x*gridDim.y, gridDim.x, bx, by);
  int m0 = by*BM, n0 = bx*BN;
  int t = threadIdx.x;
  int lane = t&63, w = t>>6;
  int wr = w>>1, wc = w&1;
  int K = K1 + K2;
  f32x4 acc[MW][NWF];
#pragma unroll
  for (int mi=0;mi<MW;mi++)
#pragma unroll
    for (int ni=0;ni<NWF;ni++) acc[mi][ni] = (f32x4){0.f,0.f,0.f,0.f};
  int srow = lane>>3;
  int cs   = ((lane&7) ^ srow)*8;
  size_t aoff1[LA], aoff2[LA];
#pragma unroll
  for (int i=0;i<LA;i++){
    int gr = m0 + i*32 + w*8 + srow;
    if (WIN) aoff1[i] = (size_t)winmap_tok(r0+gr)*K1;
    else { aoff1[i] = (size_t)gr*K1; aoff2[i] = (size_t)gr*K2; }
  }
  size_t boff[LB];
#pragma unroll
  for (int i=0;i<LB;i++)
    boff[i] = (size_t)(n0 + i*32 + w*8 + srow)*K;
  for (int k0=0; k0<K; k0+=64){
#pragma unroll
    for (int i=0;i<LA;i++){
      const u16* ap = (WIN || k0 < K1) ? A1 + aoff1[i] + k0 + cs
                                       : A2 + aoff2[i] + (k0-K1) + cs;
      gl16(ap, &As[i*32 + w*8][0]);
    }
#pragma unroll
    for (int i=0;i<LB;i++){
      gl16(Wt + boff[i] + k0 + cs, &Bs[i*32 + w*8][0]);
    }
    __syncthreads();
    int lg = lane>>4, li = lane&15;
#pragma unroll
    for (int kk=0;kk<2;kk++){
      s16x8 afr[MW], bfr[NWF];
#pragma unroll
      for (int mi=0;mi<MW;mi++){
        int lr = wr*(BM/2)+mi*16+li;
        afr[mi] = *(const s16x8*)&As[lr][(((kk<<2)+lg) ^ (lr&7))<<3];
      }
#pragma unroll
      for (int ni=0;ni<NWF;ni++){
        int lr = wc*(BN/2)+ni*16+li;
        bfr[ni] = *(const s16x8*)&Bs[lr][(((kk<<2)+lg) ^ (lr&7))<<3];
      }
#pragma unroll
      for (int mi=0;mi<MW;mi++)
#pragma unroll
        for (int ni=0;ni<NWF;ni++)
          acc[mi][ni] = __builtin_amdgcn_mfma_f32_16x16x32_bf16(afr[mi], bfr[ni], acc[mi][ni], 0,0,0);
    }
    __syncthreads();
  }
  int lg = lane>>4, li = lane&15;
#pragma unroll
  for (int mi=0;mi<MW;mi++){
#pragma unroll
    for (int ni=0;ni<NWF;ni++){
      int gn = n0 + wc*(BN/2) + ni*16 + li;
      float bv = bias ? bias[gn] : 0.f;
#pragma unroll
      for (int r=0;r<4;r++){
        int gm = m0 + wr*(BM/2) + mi*16 + lg*4 + r;
        float v = acc[mi][ni][r] + bv;
        size_t orow = WINST ? (size_t)winmap_tok(r0+gm) : (size_t)gm;
        size_t off = orow*N + gn;
        if (EPI==EPI_SILU)        v = silu_(v);
        else if (EPI==EPI_GELU)   v = gelu_(v);
        else if (EPI==EPI_SIGMUL) v = tof(other[off])*sigm_(v);
        else if (EPI==EPI_ADD)    v = v + tof(other[off]);
        else if (EPI==EPI_RELU)   v = fmaxf(v,0.f);
        else if (EPI==EPI_SIGMOID)v = sigm_(v);
        sto(outp + off, v);
      }
    }
  }
}

// -------- fp32 fallback GEMM (tiny N): out = epi(A[M,K]@W[K,N]+bias) -------
template<int EPI, typename OT, typename CT>
__global__ __launch_bounds__(256) void gemm_k(
    const u16* __restrict__ A1, const u16* __restrict__ A2, int K1, int K2,
    const float* __restrict__ W, int ldw, const float* __restrict__ bias,
    const OT* other, CT* outp, int M, int N)
{
  __shared__ float as[16][68];
  __shared__ float bs[16][64];
  int m0 = blockIdx.y*64, n0 = blockIdx.x*64;
  int t = threadIdx.x;
  int ty = t>>4, tx = t&15;
  float acc[4][4] = {{0.f}};
  int K = K1 + K2;
  int arow = t>>2, ac4 = (t&3)<<2;
  int bkr = t>>4, bnc = (t&15)<<2;
  for (int k0=0; k0<K; k0+=16){
    int gk = k0 + ac4;
    float4 av;
    if (gk < K1) av = ld4(A1 + (size_t)(m0+arow)*K1 + gk);
    else         av = ld4(A2 + (size_t)(m0+arow)*K2 + (gk-K1));
    as[ac4+0][arow]=av.x; as[ac4+1][arow]=av.y; as[ac4+2][arow]=av.z; as[ac4+3][arow]=av.w;
    int gn = n0 + bnc;
    const float* wp = W + (size_t)(k0+bkr)*ldw;
    if (gn+3 < N) {
      *(float4*)&bs[bkr][bnc] = *(const float4*)(wp + gn);
    } else {
#pragma unroll
      for (int j=0;j<4;j++) bs[bkr][bnc+j] = (gn+j<N) ? wp[gn+j] : 0.f;
    }
    __syncthreads();
#pragma unroll
    for (int kk=0; kk<16; kk++){
      float4 a4 = *(const float4*)&as[kk][ty*4];
      float4 b4 = *(const float4*)&bs[kk][tx*4];
      acc[0][0]+=a4.x*b4.x; acc[0][1]+=a4.x*b4.y; acc[0][2]+=a4.x*b4.z; acc[0][3]+=a4.x*b4.w;
      acc[1][0]+=a4.y*b4.x; acc[1][1]+=a4.y*b4.y; acc[1][2]+=a4.y*b4.z; acc[1][3]+=a4.y*b4.w;
      acc[2][0]+=a4.z*b4.x; acc[2][1]+=a4.z*b4.y; acc[2][2]+=a4.z*b4.z; acc[2][3]+=a4.z*b4.w;
      acc[3][0]+=a4.w*b4.x; acc[3][1]+=a4.w*b4.y; acc[3][2]+=a4.w*b4.z; acc[3][3]+=a4.w*b4.w;
    }
    __syncthreads();
  }
#pragma unroll
  for (int i=0;i<4;i++){
    int gm = m0 + ty*4 + i;
#pragma unroll
    for (int j=0;j<4;j++){
      int gn = n0 + tx*4 + j;
      if (gn >= N) continue;
      float v = acc[i][j] + (bias ? bias[gn] : 0.f);
      size_t off = (size_t)gm*N + gn;
      if (EPI==EPI_SILU)        v = silu_(v);
      else if (EPI==EPI_GELU)   v = gelu_(v);
      else if (EPI==EPI_SIGMUL) v = tof(other[off])*sigm_(v);
      else if (EPI==EPI_ADD)    v = v + tof(other[off]);
      else if (EPI==EPI_RELU)   v = fmaxf(v,0.f);
      else if (EPI==EPI_SIGMOID)v = sigm_(v);
      sto(outp + off, v);
    }
  }
}

// ---- fused xBC GEMM (M=64 tile) + causal conv(4) + SiLU -> XC2/XT ---------
// XCD-aware swizzle: the 5 x-tiles sharing one A-panel stay on one XCD.
__global__ __launch_bounds__(256) void xbcconv_k(
    const u16* __restrict__ A1, const u16* __restrict__ Wt,
    const float* __restrict__ cw, const float* __restrict__ cb,
    u16* __restrict__ XC, u16* __restrict__ XT)
{
  __shared__ u16 As[64][40];
  __shared__ u16 Ab[16][40];
  __shared__ u16 Bs[128][40];
  __shared__ float Cls[67][132];
  int bx, by;
  xcdswz(blockIdx.y*gridDim.x + blockIdx.x, gridDim.x*gridDim.y, gridDim.x, bx, by);
  int m0 = by*64, n0 = bx*128;
  bool first = ((m0 & 4095) == 0);
  int t = threadIdx.x;
  int lane = t&63, w = t>>6;
  int wr = w>>1, wc = w&1;
  int lg = lane>>4, li = lane&15;
  f32x4 acc[2][4], acc3[2];
#pragma unroll
  for (int mi=0;mi<2;mi++)
#pragma unroll
    for (int ni=0;ni<4;ni++) acc[mi][ni] = (f32x4){0.f,0.f,0.f,0.f};
  acc3[0]=(f32x4){0,0,0,0}; acc3[1]=(f32x4){0,0,0,0};
  for (int i=t; i<320; i+=256) ((u32*)&Ab[0][0])[i] = 0u;
  int lrow = t>>2, lc8 = (t&3)*8;
  for (int k0=0; k0<256; k0+=32){
    *(uint4*)&As[lrow][lc8] = *(const uint4*)(A1 + (size_t)(m0+lrow)*256 + k0 + lc8);
    if (t < 12 && !first){
      int r3 = t>>2, seg = t&3;
      *(uint4*)&Ab[r3][seg*8] = *(const uint4*)(A1 + (size_t)(m0-3+r3)*256 + k0 + seg*8);
    }
#pragma unroll
    for (int i=0;i<2;i++){
      int row = lrow + i*64;
      *(uint4*)&Bs[row][lc8] = *(const uint4*)(Wt + (size_t)(n0+row)*256 + k0 + lc8);
    }
    __syncthreads();
    s16x8 afr[2], bfr[4];
#pragma unroll
    for (int mi=0;mi<2;mi++)
      afr[mi] = *(const s16x8*)&As[wr*32+mi*16+li][lg*8];
#pragma unroll
    for (int ni=0;ni<4;ni++)
      bfr[ni] = *(const s16x8*)&Bs[wc*64+ni*16+li][lg*8];
#pragma unroll
    for (int mi=0;mi<2;mi++)
#pragma unroll
      for (int ni=0;ni<4;ni++)
        acc[mi][ni] = __builtin_amdgcn_mfma_f32_16x16x32_bf16(afr[mi], bfr[ni], acc[mi][ni], 0,0,0);
    {
      s16x8 abf = *(const s16x8*)&Ab[li][lg*8];
#pragma unroll
      for (int ni2=0;ni2<2;ni2++){
        s16x8 bb = *(const s16x8*)&Bs[w*32+ni2*16+li][lg*8];
        acc3[ni2] = __builtin_amdgcn_mfma_f32_16x16x32_bf16(abf, bb, acc3[ni2], 0,0,0);
      }
    }
    __syncthreads();
  }
#pragma unroll
  for (int mi=0;mi<2;mi++)
#pragma unroll
    for (int ni=0;ni<4;ni++){
      int col = wc*64 + ni*16 + li;
#pragma unroll
      for (int r=0;r<4;r++){
        int rl = wr*32 + mi*16 + lg*4 + r;
        Cls[3+rl][col] = acc[mi][ni][r];
      }
    }
  if (lg == 0){
#pragma unroll
    for (int ni2=0;ni2<2;ni2++){
      int col = w*32 + ni2*16 + li;
#pragma unroll
      for (int r=0;r<3;r++)
        Cls[r][col] = acc3[ni2][r];
    }
  }
  __syncthreads();
  int col = t & 127, half = t >> 7;
  int ch = n0 + col;
  float w0 = cw[ch*4+0], w1 = cw[ch*4+1], w2 = cw[ch*4+2], w3 = cw[ch*4+3];
  float bias = cb[ch];
  int r0 = half*32;
  float c0 = Cls[r0+0][col], c1 = Cls[r0+1][col], c2 = Cls[r0+2][col];
  u16 xtbuf[32];
  if (ch < 512){
#pragma unroll
    for (int rr=0; rr<32; rr++){
      float c3 = Cls[r0+rr+3][col];
      float v = bias + w0*c0 + w1*c1 + w2*c2 + w3*c3;
      xtbuf[rr] = f2b(silu_(v));
      c0=c1; c1=c2; c2=c3;
    }
    int g = m0 >> 8;
    u16* dst = XT + ((size_t)(g*512 + ch))*256 + (m0&255) + r0;
#pragma unroll
    for (int q=0;q<4;q++) *(uint4*)(dst + q*8) = *(const uint4*)&xtbuf[q*8];
  } else {
#pragma unroll
    for (int rr=0; rr<32; rr++){
      float c3 = Cls[r0+rr+3][col];
      float v = bias + w0*c0 + w1*c1 + w2*c2 + w3*c3;
      XC[(size_t)(m0 + r0 + rr)*128 + (ch-512)] = f2b(silu_(v));
      c0=c1; c1=c2; c2=c3;
    }
  }
}

// ----- dt softplus fused into per-chunk cumsum (writes DT and ACS) ---------
__global__ __launch_bounds__(256) void acs_k(
    const float* __restrict__ DTRAW, const float* __restrict__ dtb, const float* __restrict__ alog,
    float* __restrict__ DT_, float* __restrict__ ACS_)
{
  int wid = (blockIdx.x<<2) + (threadIdx.x>>6);
  int lane = threadIdx.x & 63;
  int c  = wid & 15;
  int bh = wid >> 4;
  int b  = bh >> 3, h = bh & 7;
  float db = dtb[h];
  float ea = __expf(alog[h]);
  size_t tok0 = (size_t)b*4096 + c*256 + lane*4;
  float v0,v1,v2,v3;
  {
    float xv, sp;
    xv = DTRAW[(tok0+0)*8 + h] + db; sp = (xv>20.f)?xv:log1pf(__expf(xv)); DT_[(tok0+0)*8+h]=sp; v0 = -sp*ea;
    xv = DTRAW[(tok0+1)*8 + h] + db; sp = (xv>20.f)?xv:log1pf(__expf(xv)); DT_[(tok0+1)*8+h]=sp; v1 = -sp*ea;
    xv = DTRAW[(tok0+2)*8 + h] + db; sp = (xv>20.f)?xv:log1pf(__expf(xv)); DT_[(tok0+2)*8+h]=sp; v2 = -sp*ea;
    xv = DTRAW[(tok0+3)*8 + h] + db; sp = (xv>20.f)?xv:log1pf(__expf(xv)); DT_[(tok0+3)*8+h]=sp; v3 = -sp*ea;
  }
  v1 += v0; v2 += v1; v3 += v2;
  float tot = v3, s = tot;
#pragma unroll
  for (int o=1;o<64;o<<=1){
    float u = __shfl_up(s, o, 64);
    if (lane >= o) s += u;
  }
  float excl = s - tot;
  float* dst = ACS_ + (size_t)bh*4096 + c*256 + lane*4;
  dst[0]=excl+v0; dst[1]=excl+v1; dst[2]=excl+v2; dst[3]=excl+v3;
}

// ------- chunk end-states via MFMA; Xt from XT; B from XC2; XCD-affinity ---
__global__ __launch_bounds__(256) void states_k(
    const u16* __restrict__ XC, const u16* __restrict__ XT,
    const float* __restrict__ DTc, const float* __restrict__ ACSc,
    float* __restrict__ ST)
{
  int b = blockIdx.x;
  int j = b & 7, s = b >> 3;
  int h = s & 7, gq = s >> 3;
  int g = j + gq*8;                 // g = bl*16 + c
  int c = g & 15, bl = g >> 4;
  __shared__ u16 Xt[64*64];
  __shared__ u16 Bt[64*64];
  int t = threadIdx.x;
  int lane = t&63, w = t>>6;
  int wr = w>>1, wc = w&1;
  int lg = lane>>4, li = lane&15;
  const float* acs = ACSc + ((size_t)(bl*8+h))*4096 + c*256;
  float aL = acs[255];
  size_t tok0 = (size_t)bl*4096 + c*256;
  f32x4 acc[2][2];
#pragma unroll
  for (int mi=0;mi<2;mi++)
#pragma unroll
    for (int ni=0;ni<2;ni++) acc[mi][ni] = (f32x4){0.f,0.f,0.f,0.f};
  int sr = t>>2, cg = t&3;
  int srch = sr>>3, srlo = sr&7;
  const u16* xtb = XT + ((size_t)(g*512) + h*64)*256;
  for (int s0=0; s0<256; s0+=64){
    __syncthreads();
    {
      int prow = t>>2, c2 = t&3;
      const u16* src = xtb + (size_t)prow*256 + s0;
      uint4 a0 = *(const uint4*)(src + c2*8);
      uint4 a1 = *(const uint4*)(src + (c2+4)*8);
      *(uint4*)&Xt[prow*64 + (vswz(prow,c2)<<3)]   = a0;
      *(uint4*)&Xt[prow*64 + (vswz(prow,c2+4)<<3)] = a1;
    }
    {
      size_t grow = tok0 + s0 + sr;
      float scl = __expf(aL - acs[s0+sr]) * DTc[grow*8 + h];
      const u16* brow_p = XC + grow*128 + cg*16;
      uint4 ba = *(const uint4*)brow_p, bb2 = *(const uint4*)(brow_p+8);
      const u16* bu = (const u16*)&ba;
#pragma unroll
      for (int jj=0;jj<8;jj++){
        int row = cg*16+jj;
        Bt[row*64 + (vswz(row,srch)<<3) + srlo] = f2b(b2f(bu[jj])*scl);
      }
      const u16* bu2 = (const u16*)&bb2;
#pragma unroll
      for (int jj=0;jj<8;jj++){
        int row = cg*16+8+jj;
        Bt[row*64 + (vswz(row,srch)<<3) + srlo] = f2b(b2f(bu2[jj])*scl);
      }
    }
    __syncthreads();
    s16x8 afr[2][2], bfr[2][2];
#pragma unroll
    for (int kk=0;kk<2;kk++){
#pragma unroll
      for (int mi=0;mi<2;mi++){
        int row = wr*32+mi*16+li;
        afr[mi][kk] = *(const s16x8*)&Xt[row*64 + (vswz(row, kk*4+lg)<<3)];
      }
#pragma unroll
      for (int ni=0;ni<2;ni++){
        int row = wc*32+ni*16+li;
        bfr[ni][kk] = *(const s16x8*)&Bt[row*64 + (vswz(row, kk*4+lg)<<3)];
      }
    }
#pragma unroll
    for (int kk=0;kk<2;kk++)
#pragma unroll
      for (int mi=0;mi<2;mi++)
#pragma unroll
        for (int ni=0;ni<2;ni++)
          acc[mi][ni] = __builtin_amdgcn_mfma_f32_16x16x32_bf16(afr[mi][kk], bfr[ni][kk], acc[mi][ni], 0,0,0);
  }
  float* dst = ST + ((size_t)(g*8 + h))*4096;
#pragma unroll
  for (int mi=0;mi<2;mi++)
#pragma unroll
    for (int ni=0;ni<2;ni++){
      int gn = wc*32 + ni*16 + li;
#pragma unroll
      for (int r=0;r<4;r++){
        int gp = wr*32 + mi*16 + lg*4 + r;
        dst[gp*64 + gn] = acc[mi][ni][r];
      }
    }
}

// ------- sequential inter-chunk scan; STIN out bf16; split over e ----------
__global__ __launch_bounds__(256) void scan_k(
    const float* __restrict__ ST, const float* __restrict__ ACSc, u16* __restrict__ STIN)
{
  int bid = blockIdx.x;              // (bl*8+h)*4 + eq
  int eq = bid & 3, h = (bid>>2)&7, bl = bid>>5;
  int t = threadIdx.x;
  float hr[4] = {0.f,0.f,0.f,0.f};
  for (int c=0;c<16;c++){
    float dec = __expf(ACSc[((size_t)(bl*8+h))*4096 + c*256 + 255]);
    size_t base = ((size_t)((bl*16+c)*8+h))*4096 + (size_t)eq*1024;
#pragma unroll
    for (int e=0;e<4;e++){
      size_t idx = base + e*256 + t;
      float st = ST[idx];
      STIN[idx] = f2b(hr[e]);
      hr[e] = hr[e]*dec + st;
    }
  }
}

// ------------ Y = Yd + Yo + d_skip*xs via MFMA; head-pair blocks -----------
__global__ __launch_bounds__(256) void ydy_k(
    const u16* __restrict__ XC, const u16* __restrict__ XT,
    const float* __restrict__ DTc,
    const float* __restrict__ ACSc, const u16* __restrict__ STIN,
    const float* __restrict__ dskip, u16* __restrict__ Y)
{
  int b = blockIdx.x;
  int j = b & 7, s = b >> 3;
  int hp = s & 3, ltp = (s>>2) & 1, gq = s >> 3;
  int g = j + gq*8;                 // g = bl*16 + c
  int c = g & 15, bl = g >> 4;
  int h0 = hp*2, h1 = h0 + 1;
  __shared__ u16 Ct[64][72];
  __shared__ u16 Sb[64][72];
  __shared__ u16 Sl[64][72];
  __shared__ u16 Vt0[64*64];
  __shared__ u16 Vt1[64*64];
  int t = threadIdx.x;
  int lane = t&63, w = t>>6;
  int wr = w>>1, wc = w&1;
  int lg = lane>>4, li = lane&15;
  const float* acs0 = ACSc + ((size_t)(bl*8+h0))*4096 + c*256;
  const float* acs1 = ACSc + ((size_t)(bl*8+h1))*4096 + c*256;
  size_t tok0 = (size_t)bl*4096 + c*256;
  int sr = t>>2;
  const u16* stin0 = STIN + ((size_t)(g*8+h0))*4096;
  const u16* stin1 = STIN + ((size_t)(g*8+h1))*4096;
  const u16* xtb0 = XT + ((size_t)(g*512) + h0*64)*256;
  const u16* xtb1 = XT + ((size_t)(g*512) + h1*64)*256;
  float dsk0 = dskip[h0], dsk1 = dskip[h1];
  for (int pp=0; pp<2; pp++){
    int lt = pp ? (3-ltp) : ltp;
    int l0 = lt*64;
#pragma unroll
    for (int it=0; it<2; it++){
      int seg = (t&3) + it*4;
      *(uint4*)&Ct[sr][seg*8] = *(const uint4*)(XC + (tok0+l0+sr)*128 + 64 + seg*8);
    }
    float acsl0[2][4], acsl1[2][4];
#pragma unroll
    for (int mi=0;mi<2;mi++)
#pragma unroll
      for (int r=0;r<4;r++){
        int idx = l0 + wr*32 + mi*16 + lg*4 + r;
        acsl0[mi][r] = acs0[idx];
        acsl1[mi][r] = acs1[idx];
      }
    f32x4 accP0[2][2], accP1[2][2];
    __syncthreads();
    // Yo (head0) -> accP0 init
    {
      f32x4 aO[2][2];
#pragma unroll
      for (int mi=0;mi<2;mi++)
#pragma unroll
        for (int ni=0;ni<2;ni++) aO[mi][ni]=(f32x4){0,0,0,0};
#pragma unroll
      for (int kk=0;kk<2;kk++){
        s16x8 bfr[2];
#pragma unroll
        for (int ni=0;ni<2;ni++){
          int p = wc*32 + ni*16 + li;
          bfr[ni] = *(const s16x8*)(stin0 + p*64 + kk*32 + lg*8);
        }
#pragma unroll
        for (int mi=0;mi<2;mi++){
          s16x8 afr = *(const s16x8*)&Ct[wr*32+mi*16+li][kk*32+lg*8];
#pragma unroll
          for (int ni=0;ni<2;ni++)
            aO[mi][ni] = __builtin_amdgcn_mfma_f32_16x16x32_bf16(afr, bfr[ni], aO[mi][ni], 0,0,0);
        }
      }
#pragma unroll
      for (int mi=0;mi<2;mi++)
#pragma unroll
        for (int ni=0;ni<2;ni++)
#pragma unroll
          for (int r=0;r<4;r++)
            accP0[mi][ni][r] = __expf(acsl0[mi][r]) * aO[mi][ni][r];
    }
    // Yo (head1) -> accP1 init
    {
      f32x4 aO[2][2];
#pragma unroll
      for (int mi=0;mi<2;mi++)
#pragma unroll
        for (int ni=0;ni<2;ni++) aO[mi][ni]=(f32x4){0,0,0,0};
#pragma unroll
      for (int kk=0;kk<2;kk++){
        s16x8 bfr[2];
#pragma unroll
        for (int ni=0;ni<2;ni++){
          int p = wc*32 + ni*16 + li;
          bfr[ni] = *(const s16x8*)(stin1 + p*64 + kk*32 + lg*8);
        }
#pragma unroll
        for (int mi=0;mi<2;mi++){
          s16x8 afr = *(const s16x8*)&Ct[wr*32+mi*16+li][kk*32+lg*8];
#pragma unroll
          for (int ni=0;ni<2;ni++)
            aO[mi][ni] = __builtin_amdgcn_mfma_f32_16x16x32_bf16(afr, bfr[ni], aO[mi][ni], 0,0,0);
        }
      }
#pragma unroll
      for (int mi=0;mi<2;mi++)
#pragma unroll
        for (int ni=0;ni<2;ni++)
#pragma unroll
          for (int r=0;r<4;r++)
            accP1[mi][ni][r] = __expf(acsl1[mi][r]) * aO[mi][ni][r];
    }
    for (int sb=0; sb<=lt; sb++){
      int s0 = sb*64;
      // stage B (shared) + V for both heads
#pragma unroll
      for (int it=0; it<2; it++){
        int seg = (t&3) + it*4;
        *(uint4*)&Sb[sr][seg*8] = *(const uint4*)(XC + (tok0+s0+sr)*128 + seg*8);
      }
      {
        int prow = t>>2, c2 = t&3;
        const u16* src0 = xtb0 + (size_t)prow*256 + s0;
        uint4 a0 = *(const uint4*)(src0 + c2*8);
        uint4 a1 = *(const uint4*)(src0 + (c2+4)*8);
        *(uint4*)&Vt0[prow*64 + (vswz(prow,c2)<<3)]   = a0;
        *(uint4*)&Vt0[prow*64 + (vswz(prow,c2+4)<<3)] = a1;
        const u16* src1 = xtb1 + (size_t)prow*256 + s0;
        uint4 b0 = *(const uint4*)(src1 + c2*8);
        uint4 b1 = *(const uint4*)(src1 + (c2+4)*8);
        *(uint4*)&Vt1[prow*64 + (vswz(prow,c2)<<3)]   = b0;
        *(uint4*)&Vt1[prow*64 + (vswz(prow,c2+4)<<3)] = b1;
      }
      __syncthreads();
      // shared S = C_l * B_s^T
      f32x4 sacc[2][2];
#pragma unroll
      for (int mi=0;mi<2;mi++)
#pragma unroll
        for (int ni=0;ni<2;ni++) sacc[mi][ni]=(f32x4){0,0,0,0};
#pragma unroll
      for (int kk=0;kk<2;kk++){
        s16x8 bfr[2];
#pragma unroll
        for (int ni=0;ni<2;ni++)
          bfr[ni] = *(const s16x8*)&Sb[wc*32+ni*16+li][kk*32+lg*8];
#pragma unroll
        for (int mi=0;mi<2;mi++){
          s16x8 afr = *(const s16x8*)&Ct[wr*32+mi*16+li][kk*32+lg*8];
#pragma unroll
          for (int ni=0;ni<2;ni++)
            sacc[mi][ni] = __builtin_amdgcn_mfma_f32_16x16x32_bf16(afr, bfr[ni], sacc[mi][ni], 0,0,0);
        }
      }
      // ---- head 0: P -> Sl, PV ----
#pragma unroll
      for (int ni=0;ni<2;ni++){
        int cs2 = wc*32 + ni*16 + li;
        int gsj = s0 + cs2;
        float acss = acs0[gsj];
        float dts = DTc[(tok0+gsj)*8 + h0];
#pragma unroll
        for (int mi=0;mi<2;mi++){
#pragma unroll
          for (int r=0;r<4;r++){
            int lrow = wr*32 + mi*16 + lg*4 + r;
            int gl = l0 + lrow;
            float wgt = (gsj <= gl) ? __expf(acsl0[mi][r] - acss)*dts : 0.f;
            Sl[lrow][cs2] = f2b(sacc[mi][ni][r] * wgt);
          }
        }
      }
      __syncthreads();
#pragma unroll
      for (int kk=0;kk<2;kk++){
        s16x8 bfr[2];
#pragma unroll
        for (int ni=0;ni<2;ni++){
          int p = wc*32+ni*16+li;
          bfr[ni] = *(const s16x8*)&Vt0[p*64 + (vswz(p, kk*4+lg)<<3)];
        }
#pragma unroll
        for (int mi=0;mi<2;mi++){
          s16x8 afr = *(const s16x8*)&Sl[wr*32+mi*16+li][kk*32+lg*8];
#pragma unroll
          for (int ni=0;ni<2;ni++)
            accP0[mi][ni] = __builtin_amdgcn_mfma_f32_16x16x32_bf16(afr, bfr[ni], accP0[mi][ni], 0,0,0);
        }
      }
      __syncthreads();
      // ---- head 1: P -> Sl, PV ----
#pragma unroll
      for (int ni=0;ni<2;ni++){
        int cs2 = wc*32 + ni*16 + li;
        int gsj = s0 + cs2;
        float acss = acs1[gsj];
        float dts = DTc[(tok0+gsj)*8 + h1];
#pragma unroll
        for (int mi=0;mi<2;mi++){
#pragma unroll
          for (int r=0;r<4;r++){
            int lrow = wr*32 + mi*16 + lg*4 + r;
            int gl = l0 + lrow;
            float wgt = (gsj <= gl) ? __expf(acsl1[mi][r] - acss)*dts : 0.f;
            Sl[lrow][cs2] = f2b(sacc[mi][ni][r] * wgt);
          }
        }
      }
      __syncthreads();
#pragma unroll
      for (int kk=0;kk<2;kk++){
        s16x8 bfr[2];
#pragma unroll
        for (int ni=0;ni<2;ni++){
          int p = wc*32+ni*16+li;
          bfr[ni] = *(const s16x8*)&Vt1[p*64 + (vswz(p, kk*4+lg)<<3)];
        }
#pragma unroll
        for (int mi=0;mi<2;mi++){
          s16x8 afr = *(const s16x8*)&Sl[wr*32+mi*16+li][kk*32+lg*8];
#pragma unroll
          for (int ni=0;ni<2;ni++)
            accP1[mi][ni] = __builtin_amdgcn_mfma_f32_16x16x32_bf16(afr, bfr[ni], accP1[mi][ni], 0,0,0);
        }
      }
      __syncthreads();
    }
    // epilogue: out(h0) -> Sb, out(h1) -> Ct, then store both
#pragma unroll
    for (int mi=0;mi<2;mi++){
#pragma unroll
      for (int ni=0;ni<2;ni++){
        int p = wc*32 + ni*16 + li;
#pragma unroll
        for (int r=0;r<4;r++){
          int lrow = wr*32 + mi*16 + lg*4 + r;
          int voff = p*64 + (vswz(p, lrow>>3)<<3) + (lrow&7);
          float xsv0 = b2f(Vt0[voff]);
          float xsv1 = b2f(Vt1[voff]);
          Sb[lrow][p] = f2b(accP0[mi][ni][r] + dsk0*xsv0);
          Ct[lrow][p] = f2b(accP1[mi][ni][r] + dsk1*xsv1);
        }
      }
    }
    __syncthreads();
#pragma unroll
    for (int it=0; it<2; it++){
      int seg = (t&3) + it*4;
      *(uint4*)(Y + (tok0+l0+sr)*512 + h0*64 + seg*8) = *(const uint4*)&Sb[sr][seg*8];
      *(uint4*)(Y + (tok0+l0+sr)*512 + h1*64 + seg*8) = *(const uint4*)&Ct[sr][seg*8];
    }
    __syncthreads();
  }
}

// ---------------- u = y*silu(z); RMSNorm*w over 512 (in place) -------------
__global__ __launch_bounds__(256) void urms_k(
    u16* Y, const u16* __restrict__ Z, const float* __restrict__ nw)
{
  int tok = blockIdx.x*4 + (threadIdx.x>>6);
  int lane = threadIdx.x & 63;
  size_t base = (size_t)tok*512 + lane*8;
  float y[8], z[8], u[8];
  ld8(Y+base, y); ld8(Z+base, z);
  float ss=0.f;
#pragma unroll
  for (int e=0;e<8;e++){ u[e] = y[e]*silu_(z[e]); ss += u[e]*u[e]; }
  ss = wsum_(ss);
  float r = rsqrtf(ss*(1.f/512.f) + 1e-5f);
  float4 w0 = *(const float4*)(nw + lane*8);
  float4 w1 = *(const float4*)(nw + lane*8 + 4);
  float o[8];
  o[0]=u[0]*r*w0.x; o[1]=u[1]*r*w0.y; o[2]=u[2]*r*w0.z; o[3]=u[3]*r*w0.w;
  o[4]=u[4]*r*w1.x; o[5]=u[5]*r*w1.y; o[6]=u[6]*r*w1.z; o[7]=u[7]*r*w1.w;
  st8(Y+base, o);
}

// ------------ window attention via MFMA, block per (window, head) ----------
__global__ __launch_bounds__(256) void attn_k(
    const u16* __restrict__ QKV, const float* __restrict__ rpb, u16* __restrict__ OW)
{
  int win = blockIdx.x;
  int wid = win & 63;
  int head = blockIdx.y;
  __shared__ u16 Qs[64][40];
  __shared__ u16 Ks[64][40];
  __shared__ u16 Vt[32][72];
  __shared__ u16 Pl[64][72];
  __shared__ float rl[225];
  __shared__ int rid[64];
  int t = threadIdx.x;
  int lane = t&63, w = t>>6;
  int lg = lane>>4, li = lane&15;
  const float scale = 0.17677669529663687f;
  {
    int row = t>>2, seg = t&3;
    const u16* base = QKV + ((size_t)win*64 + row)*768 + head*32 + seg*8;
    uint4 q = *(const uint4*)base;
    const u16* qe = (const u16*)&q;
    u16 qs8[8];
#pragma unroll
    for (int jq=0;jq<8;jq++) qs8[jq] = f2b(b2f(qe[jq])*scale);
    *(uint4*)&Qs[row][seg*8] = *(const uint4*)qs8;
    *(uint4*)&Ks[row][seg*8] = *(const uint4*)(base + 256);
    uint4 v = *(const uint4*)(base + 512);
    const u16* ve = (const u16*)&v;
#pragma unroll
    for (int jq=0;jq<8;jq++) Vt[seg*8+jq][row] = ve[jq];
  }
  if (t < 225) rl[t] = rpb[t*8 + head];
  if (t < 64){
    int h2 = ((wid>>3)<<3) + (t>>3);
    int w2 = ((wid&7)<<3) + (t&7);
    int rh = (h2<56)?0:((h2<60)?1:2);
    int rw = (w2<56)?0:((w2<60)?1:2);
    rid[t] = rh*3 + rw;
  }
  __syncthreads();
  f32x4 sc[4];
  {
    s16x8 qf = *(const s16x8*)&Qs[w*16+li][lg*8];
#pragma unroll
    for (int ni=0;ni<4;ni++){
      s16x8 kf = *(const s16x8*)&Ks[ni*16+li][lg*8];
      sc[ni] = __builtin_amdgcn_mfma_f32_16x16x32_bf16(qf, kf, (f32x4){0,0,0,0}, 0,0,0);
    }
  }
  float inv[4];
#pragma unroll
  for (int r=0;r<4;r++){
    int i = w*16 + lg*4 + r;
    int ridi = rid[i];
    float vv[4];
    float m = -1e30f;
#pragma unroll
    for (int ni=0;ni<4;ni++){
      int jj = ni*16 + li;
      float sv = sc[ni][r] + rl[((i>>3)-(jj>>3)+7)*15 + ((i&7)-(jj&7)+7)];
      if (ridi != rid[jj]) sv -= 100.f;
      vv[ni] = sv;
      m = fmaxf(m, sv);
    }
#pragma unroll
    for (int o=1;o<16;o<<=1) m = fmaxf(m, __shfl_xor(m, o, 64));
    float sum = 0.f;
#pragma unroll
    for (int ni=0;ni<4;ni++){ vv[ni] = __expf(vv[ni]-m); sum += vv[ni]; }
#pragma unroll
    for (int o=1;o<16;o<<=1) sum += __shfl_xor(sum, o, 64);
    inv[r] = 1.f/sum;
#pragma unroll
    for (int ni=0;ni<4;ni++) Pl[i][ni*16+li] = f2b(vv[ni]);
  }
  __syncthreads();
  f32x4 oacc[2];
  oacc[0]=(f32x4){0,0,0,0}; oacc[1]=(f32x4){0,0,0,0};
#pragma unroll
  for (int kk=0;kk<2;kk++){
    s16x8 pf = *(const s16x8*)&Pl[w*16+li][kk*32+lg*8];
#pragma unroll
    for (int ni=0;ni<2;ni++){
      s16x8 vf = *(const s16x8*)&Vt[ni*16+li][kk*32+lg*8];
      oacc[ni] = __builtin_amdgcn_mfma_f32_16x16x32_bf16(pf, vf, oacc[ni], 0,0,0);
    }
  }
#pragma unroll
  for (int ni=0;ni<2;ni++)
#pragma unroll
    for (int r=0;r<4;r++)
      Pl[w*16+lg*4+r][ni*16+li] = f2b(oacc[ni][r]*inv[r]);
  __syncthreads();
  {
    int row = t>>2, seg = t&3;
    *(uint4*)(OW + ((size_t)win*64 + row)*256 + head*32 + seg*8) = *(const uint4*)&Pl[row][seg*8];
  }
}

// ---------------- host ------------------------------------------------------
extern "C" void kernel_launch(void* const* d_in, const int* in_sizes, int n_in,
                              void* d_out, int out_size, void* d_ws, size_t ws_size,
                              hipStream_t stream)
{
  (void)in_sizes; (void)n_in; (void)out_size;
  const size_t OFF_XN   = 0;
  const size_t OFF_XNS  = 16777216;
  const size_t OFF_SP   = 33554432;
  const size_t OFF_DTRAW= 50331648;
  const size_t OFF_DT   = 51380224;
  const size_t OFF_ACS  = 53477376;
  const size_t OFF_WTS  = 54525952;
  const size_t ARO      = 58195968;
  int NB = 0;
  if      (ws_size >= ARO + 8ull*14680064) NB = 8;
  else if (ws_size >= ARO + 4ull*14680064) NB = 4;
  else if (ws_size >= ARO + 2ull*14680064) NB = 2;
  else if (ws_size >= ARO + 1ull*14680064) NB = 1;
  else return;
  int NC = 8 / NB;
  int RJ = (NB==8)?32768 : (NB==4)?16384 : (NB==2)?8192 : 4096;

  const float* x       = (const float*)d_in[0];
  const float* ln1_w   = (const float*)d_in[1];
  const float* ln1_b   = (const float*)d_in[2];
  const float* ns_w    = (const float*)d_in[3];
  const float* ns_b    = (const float*)d_in[4];
  const float* m_win   = (const float*)d_in[5];
  const float* m_conv_w= (const float*)d_in[6];
  const float* m_conv_b= (const float*)d_in[7];
  const float* m_dt_b  = (const float*)d_in[8];
  const float* m_a_log = (const float*)d_in[9];
  const float* m_d     = (const float*)d_in[10];
  const float* m_norm_w= (const float*)d_in[11];
  const float* m_wout  = (const float*)d_in[12];
  const float* tm_w1   = (const float*)d_in[13];
  const float* tm_b1   = (const float*)d_in[14];
  const float* tm_w2   = (const float*)d_in[15];
  const float* tm_b2   = (const float*)d_in[16];
  const float* nt_w    = (const float*)d_in[17];
  const float* nt_b    = (const float*)d_in[18];
  const float* qkv_w   = (const float*)d_in[19];
  const float* qkv_b   = (const float*)d_in[20];
  const float* rpb     = (const float*)d_in[21];
  const float* gate_w  = (const float*)d_in[22];
  const float* gate_b  = (const float*)d_in[23];
  const float* proj_w  = (const float*)d_in[24];
  const float* proj_b  = (const float*)d_in[25];
  const float* cg_w1a  = (const float*)d_in[26];
  const float* cg_b1a  = (const float*)d_in[27];
  const float* cg_w2a  = (const float*)d_in[28];
  const float* cg_b2a  = (const float*)d_in[29];
  const float* cg_w1m  = (const float*)d_in[30];
  const float* cg_b1m  = (const float*)d_in[31];
  const float* cg_w2m  = (const float*)d_in[32];
  const float* cg_b2m  = (const float*)d_in[33];
  const float* cg_wf   = (const float*)d_in[34];
  const float* cg_bf   = (const float*)d_in[35];
  const float* ln2_w   = (const float*)d_in[36];
  const float* ln2_b   = (const float*)d_in[37];
  const float* mlp_w1  = (const float*)d_in[38];
  const float* mlp_b1  = (const float*)d_in[39];
  const float* mlp_w2  = (const float*)d_in[40];
  const float* mlp_b2  = (const float*)d_in[41];
  float* dout = (float*)d_out;
  char* ws = (char*)d_ws;

  u16*  XN   = (u16*)(ws + OFF_XN);
  u16*  XNS  = (u16*)(ws + OFF_XNS);
  u16*  SP   = (u16*)(ws + OFF_SP);
  float* DTRAW = (float*)(ws + OFF_DTRAW);
  float* DT  = (float*)(ws + OFF_DT);
  float* ACS = (float*)(ws + OFF_ACS);
  u16*  WTS  = (u16*)(ws + OFF_WTS);
  u16* WT_XBC = WTS + 0;
  u16* WT_Z   = WTS + 163840;
  u16* WT_WOUT= WTS + 294912;
  u16* WT_TM1 = WTS + 425984;
  u16* WT_TM2 = WTS + 491520;
  u16* WT_QKV = WTS + 557056;
  u16* WT_GATE= WTS + 753664;
  u16* WT_PROJ= WTS + 819200;
  u16* WT_W2A = WTS + 884736;
  u16* WT_W2M = WTS + 901120;
  u16* WT_WF  = WTS + 917504;
  u16* WT_MLP1= WTS + 1048576;
  u16* WT_MLP2= WTS + 1310720;
  u16* WT_W1A = WTS + 1572864;
  u16* WT_W1M = WTS + 1589248;
  char* AR = ws + ARO;
  u16*  XCc   = (u16*)AR;
  u16*  Zc    = (u16*)(AR + (size_t)NB*5242880);
  u16*  XTc   = Zc;
  u16*  STINc = (u16*)(AR + (size_t)NB*9437184);
  float* STc  = (float*)(AR + (size_t)NB*10485760);
  u16*  Yc    = (u16*)(AR + (size_t)NB*10485760);
  u16*  QKVc  = (u16*)AR;
  u16*  OWc   = (u16*)(AR + (size_t)NB*6291456);
  u16*  TBUF  = (u16*)AR;
  u16*  XM    = XNS;
  u16*  XA    = XN;
  u16*  CGHA  = (u16*)AR;
  u16*  CGHM  = (u16*)(AR + 4194304);
  u16*  LNc   = (u16*)AR;
  u16*  MHc   = (u16*)(AR + (size_t)RJ*512);

  const size_t TB = 4096*256;
  const size_t H2 = 16384*256;

  // Phase 0: all weight transposes in one launch
  WtTab tab;
  tab.d[0]  = { m_win+512, WT_XBC, 1160, 256, 8, 20 };
  tab.d[1]  = { m_win,     WT_Z,   1160, 256, 8, 16 };
  tab.d[2]  = { m_wout,    WT_WOUT, 256, 512, 16, 8 };
  tab.d[3]  = { tm_w1,     WT_TM1,  256, 512, 16, 8 };
  tab.d[4]  = { tm_w2,     WT_TM2,  256, 256, 8, 8 };
  tab.d[5]  = { qkv_w,     WT_QKV,  768, 256, 8, 24 };
  tab.d[6]  = { gate_w,    WT_GATE, 256, 256, 8, 8 };
  tab.d[7]  = { proj_w,    WT_PROJ, 256, 256, 8, 8 };
  tab.d[8]  = { cg_w2a,    WT_W2A,  256, 64, 2, 8 };
  tab.d[9]  = { cg_w2m,    WT_W2M,  256, 64, 2, 8 };
  tab.d[10] = { cg_wf,     WT_WF,   256, 512, 16, 8 };
  tab.d[11] = { mlp_w1,    WT_MLP1,1024, 256, 8, 32 };
  tab.d[12] = { mlp_w2,    WT_MLP2, 256,1024, 32, 8 };
  tab.d[13] = { cg_w1a,    WT_W1A,   64, 256, 8, 2 };
  tab.d[14] = { cg_w1m,    WT_W1M,   64, 256, 8, 2 };
  int ntiles = 0;
  for (int i=0;i<15;i++) ntiles += tab.d[i].kb * tab.d[i].nt;
  wtall_k<<<ntiles,256,0,stream>>>(tab);

  // Phase A
  ln2x_k<<<8192,256,0,stream>>>(x, ln1_w, ln1_b, ns_w, ns_b, XN, XNS);
  gemm_k<EPI_NONE,float,float><<<dim3(1,512),256,0,stream>>>(XNS,nullptr,256,0, m_win+1152,1160, nullptr, nullptr, DTRAW, 32768,8);
  acs_k<<<256,256,0,stream>>>(DTRAW, m_dt_b, m_a_log, DT, ACS);

  // Phases B..F per chunk of NB batches
  for (int cc=0; cc<NC; cc++){
    int cb0 = cc*NB;
    const u16* XNSc = XNS + (size_t)cb0*TB;
    const float* DTcp = DT + (size_t)cb0*32768;
    const float* ACScp = ACS + (size_t)cb0*32768;
    xbcconv_k<<<dim3(5,NB*64),256,0,stream>>>(XNSc, WT_XBC, m_conv_w, m_conv_b, XCc, XTc);
    states_k<<<NB*128,256,0,stream>>>(XCc, XTc, DTcp, ACScp, STc);
    scan_k<<<NB*32,256,0,stream>>>(STc, ACScp, STINc);
    ydy_k<<<NB*128,256,0,stream>>>(XCc, XTc, DTcp, ACScp, STINc, m_d, Yc);
    mgemm_k<128,128,EPI_NONE,false,false,float,u16><<<dim3(4,NB*32),256,0,stream>>>(XNSc,nullptr,256,0, WT_Z, nullptr, nullptr, Zc, 512, 0);
    urms_k<<<NB*1024,256,0,stream>>>(Yc, Zc, m_norm_w);
    mgemm_k<64,128,EPI_ADD,false,false,u16,u16><<<dim3(2,NB*64),256,0,stream>>>(Yc,nullptr,512,0, WT_WOUT, nullptr, XN + (size_t)cb0*TB, SP + (size_t)cb0*TB, 256, 0);
  }

  // Phase G: tmix (BM=64 for occupancy)
  mgemm_k<64,128,EPI_SILU,false,false,float,u16><<<dim3(2,256),256,0,stream>>>(SP, SP+H2, 256,256, WT_TM1, tm_b1, nullptr, TBUF, 256, 0);
  mgemm_k<64,128,EPI_ADD,false,false,u16,u16><<<dim3(2,256),256,0,stream>>>(TBUF,nullptr,256,0, WT_TM2, tm_b2, SP, XM, 256, 0);
  ln_k<u16><<<4096,256,0,stream>>>(XM, nt_w, nt_b, XM);
  mgemm_k<64,128,EPI_SILU,false,false,float,u16><<<dim3(2,256),256,0,stream>>>(SP+H2, XM, 256,256, WT_TM1, tm_b1, nullptr, TBUF, 256, 0);
  mgemm_k<64,128,EPI_ADD,false,false,u16,u16><<<dim3(2,256),256,0,stream>>>(TBUF,nullptr,256,0, WT_TM2, tm_b2, SP+H2, XM+H2, 256, 0);
  ln_k<u16><<<4096,256,0,stream>>>(XM+H2, nt_w, nt_b, XM+H2);

  // Phase H: window attention
  for (int cc=0; cc<NC; cc++){
    int r0 = cc*NB*4096;
    mgemm_k<128,128,EPI_NONE,true,false,float,u16><<<dim3(6,NB*32),256,0,stream>>>(XN,nullptr,256,0, WT_QKV, qkv_b, nullptr, QKVc, 768, r0);
    attn_k<<<dim3(NB*64,8),256,0,stream>>>(QKVc, rpb, OWc);
    mgemm_k<64,128,EPI_SIGMUL,true,false,u16,u16><<<dim3(2,NB*64),256,0,stream>>>(XN,nullptr,256,0, WT_GATE, gate_b, OWc, OWc, 256, r0);
    mgemm_k<64,128,EPI_NONE,false,true,float,u16><<<dim3(2,NB*64),256,0,stream>>>(OWc,nullptr,256,0, WT_PROJ, proj_b, nullptr, XA, 256, r0);
  }

  // Phase I: cross gates (BM=64 where N=256)
  mgemm_k<128,64,EPI_RELU,false,false,float,u16><<<dim3(1,256),256,0,stream>>>(XA,nullptr,256,0, WT_W1A, cg_b1a, nullptr, CGHA, 64, 0);
  mgemm_k<128,64,EPI_RELU,false,false,float,u16><<<dim3(1,256),256,0,stream>>>(XM,nullptr,256,0, WT_W1M, cg_b1m, nullptr, CGHM, 64, 0);
  mgemm_k<64,128,EPI_SIGMUL,false,false,u16,u16><<<dim3(2,512),256,0,stream>>>(CGHA,nullptr,64,0, WT_W2A, cg_b2a, XM, XM, 256, 0);
  mgemm_k<64,128,EPI_SIGMUL,false,false,u16,u16><<<dim3(2,512),256,0,stream>>>(CGHM,nullptr,64,0, WT_W2M, cg_b2m, XA, XA, 256, 0);
  mgemm_k<64,128,EPI_ADD,false,false,float,float><<<dim3(2,512),256,0,stream>>>(XM, XA, 256,256, WT_WF, cg_bf, x, dout, 256, 0);

  // Phase J: MLP (MLP2 at BM=64)
  for (int q=0; q<32768/RJ; q++){
    float* XOq = dout + (size_t)q*RJ*256;
    ln_k<float><<<RJ/4,256,0,stream>>>(XOq, ln2_w, ln2_b, LNc);
    mgemm_k<128,128,EPI_GELU,false,false,float,u16><<<dim3(8,RJ/128),256,0,stream>>>(LNc,nullptr,256,0, WT_MLP1, mlp_b1, nullptr, MHc, 1024, 0);
    mgemm_k<64,128,EPI_ADD,false,false,float,float><<<dim3(2,RJ/64),256,0,stream>>>(MHc,nullptr,1024,0, WT_MLP2, mlp_b2, XOq, XOq, 256, 0);
  }
}

// Round 22
// 519.048 us; speedup vs baseline: 1.0197x; 1.0197x over previous
//
#include <hip/hip_runtime.h>
#include <math.h>

// twoB=8, L=4096 (H=W=64), C=256, d_inner=512, nh_m=8, hd=64, D_STATE=64,
// conv_dim=640, zx width=1160, CHUNK=256 (16 chunks/batch), WS=8, SS=4, NH=8, Dh=32.
// XC2: [tok][128] = B(64) || C(64).  XT: [g][ch<512][s] transposed conv-x.

#define DEVI static __device__ __forceinline__
typedef unsigned short u16;
typedef unsigned int   u32;
typedef __attribute__((ext_vector_type(8))) short s16x8;
typedef __attribute__((ext_vector_type(4))) float f32x4;

DEVI float sigm_(float x){ return 1.f/(1.f+__expf(-x)); }
DEVI float silu_(float x){ return x/(1.f+__expf(-x)); }
// tanh-form GELU via sigmoid identity: 0.5x(1+tanh(y)) == x*sigmoid(2y)
DEVI float gelu_(float x){
  return x * sigm_(x*(1.5957691216f + 0.0713548162f*x*x));
}
DEVI float wsum_(float v){
#pragma unroll
  for (int o=32;o>0;o>>=1) v += __shfl_xor(v,o,64);
  return v;
}

DEVI float b2f(u16 u){ union{u32 i; float f;} v; v.i = ((u32)u)<<16; return v.f; }
DEVI u16 f2b(float f){ union{float f; u32 i;} v; v.f=f; u32 r = v.i + 0x7fffu + ((v.i>>16)&1u); return (u16)(r>>16); }
DEVI float4 ld4(const float* p){ return *(const float4*)p; }
DEVI float4 ld4(const u16* p){
  uint2 r = *(const uint2*)p;
  return make_float4(b2f((u16)(r.x&0xffff)), b2f((u16)(r.x>>16)),
                     b2f((u16)(r.y&0xffff)), b2f((u16)(r.y>>16)));
}
DEVI void st4(u16* p, float a, float b, float c, float d){
  uint2 r; r.x = (u32)f2b(a) | ((u32)f2b(b)<<16); r.y = (u32)f2b(c) | ((u32)f2b(d)<<16);
  *(uint2*)p = r;
}
DEVI void st4(float* p, float a, float b, float c, float d){
  *(float4*)p = make_float4(a,b,c,d);
}
DEVI void ld8(const u16* p, float* f){
  uint4 r = *(const uint4*)p;
  f[0]=b2f((u16)(r.x&0xffff)); f[1]=b2f((u16)(r.x>>16));
  f[2]=b2f((u16)(r.y&0xffff)); f[3]=b2f((u16)(r.y>>16));
  f[4]=b2f((u16)(r.z&0xffff)); f[5]=b2f((u16)(r.z>>16));
  f[6]=b2f((u16)(r.w&0xffff)); f[7]=b2f((u16)(r.w>>16));
}
DEVI void st8(u16* p, const float* f){
  uint4 r;
  r.x=(u32)f2b(f[0])|((u32)f2b(f[1])<<16); r.y=(u32)f2b(f[2])|((u32)f2b(f[3])<<16);
  r.z=(u32)f2b(f[4])|((u32)f2b(f[5])<<16); r.w=(u32)f2b(f[6])|((u32)f2b(f[7])<<16);
  *(uint4*)p = r;
}
DEVI float tof(float v){ return v; }
DEVI float tof(u16 v){ return b2f(v); }
DEVI void sto(float* p, float v){ *p = v; }
DEVI void sto(u16* p, float v){ *p = f2b(v); }

// swizzle: spread 16B chunks of a [64-row][64-col u16] transposed tile
DEVI int vswz(int row, int ch){ return ch ^ ((row&7) ^ ((row>>3)&7)); }

// async global->LDS, 16B per lane; lds base must be wave-uniform.
DEVI void gl16(const u16* g, u16* l){
  __builtin_amdgcn_global_load_lds(
      (const __attribute__((address_space(1))) u32*)g,
      (__attribute__((address_space(3))) u32*)l, 16, 0, 0);
}

// XCD-aware remap of a linear block id (bijective when nwg%8==0)
DEVI void xcdswz(int lin, int nwg, int gx, int& bx, int& by){
  if ((nwg & 7) == 0){
    int nl = (lin & 7)*(nwg >> 3) + (lin >> 3);
    bx = nl % gx; by = nl / gx;
  } else { bx = lin % gx; by = lin / gx; }
}

// window row -> token map (roll by -4, 8x8 windows over 64x64, per batch)
DEVI int winmap_tok(int r){
  int win = r>>6, tk = r&63;
  int b = win>>6, wid = win&63;
  int h2 = ((wid>>3)<<3) + (tk>>3);
  int w2 = ((wid&7)<<3) + (tk&7);
  int hh = (h2+4)&63, wwp = (w2+4)&63;
  return b*4096 + hh*64 + wwp;
}

// ---------------- fused LN(x)->xn, LN(xn)->xns (bf16 outs) -----------------
__global__ __launch_bounds__(256) void ln2x_k(
    const float* __restrict__ x, const float* __restrict__ w1, const float* __restrict__ b1,
    const float* __restrict__ w2, const float* __restrict__ b2,
    u16* __restrict__ xn, u16* __restrict__ xns)
{
  int tok = blockIdx.x*4 + (threadIdx.x>>6);
  int lane = threadIdx.x & 63;
  size_t base = (size_t)tok*256 + lane*4;
  float4 v = *(const float4*)(x + base);
  float mu = wsum_(v.x+v.y+v.z+v.w) * (1.f/256.f);
  float ax=v.x-mu, ay=v.y-mu, az=v.z-mu, aw=v.w-mu;
  float var = wsum_(ax*ax+ay*ay+az*az+aw*aw) * (1.f/256.f);
  float r = rsqrtf(var+1e-5f);
  float4 wv = *(const float4*)(w1+lane*4);
  float4 bv = *(const float4*)(b1+lane*4);
  float ox=ax*r*wv.x+bv.x, oy=ay*r*wv.y+bv.y, oz=az*r*wv.z+bv.z, ow=aw*r*wv.w+bv.w;
  st4(xn + base, ox, oy, oz, ow);
  float mu2 = wsum_(ox+oy+oz+ow)*(1.f/256.f);
  float bx=ox-mu2, by=oy-mu2, bz=oz-mu2, bw=ow-mu2;
  float var2 = wsum_(bx*bx+by*by+bz*bz+bw*bw)*(1.f/256.f);
  float r2 = rsqrtf(var2+1e-5f);
  float4 w2v = *(const float4*)(w2+lane*4);
  float4 b2v = *(const float4*)(b2+lane*4);
  st4(xns + base, bx*r2*w2v.x+b2v.x, by*r2*w2v.y+b2v.y, bz*r2*w2v.z+b2v.z, bw*r2*w2v.w+b2v.w);
}

// ---------------- generic LayerNorm (C=256), bf16 out ----------------------
template<typename IT>
__global__ __launch_bounds__(256) void ln_k(
    const IT* __restrict__ in, const float* __restrict__ w, const float* __restrict__ b,
    u16* __restrict__ outp)
{
  int tok = blockIdx.x*4 + (threadIdx.x>>6);
  int lane = threadIdx.x & 63;
  size_t base = (size_t)tok*256 + lane*4;
  float4 v = ld4(in + base);
  float mu = wsum_(v.x+v.y+v.z+v.w) * (1.f/256.f);
  float ax=v.x-mu, ay=v.y-mu, az=v.z-mu, aw=v.w-mu;
  float var = wsum_(ax*ax+ay*ay+az*az+aw*aw) * (1.f/256.f);
  float r = rsqrtf(var+1e-5f);
  float4 wv = *(const float4*)(w+lane*4);
  float4 bv = *(const float4*)(b+lane*4);
  st4(outp + base, ax*r*wv.x+bv.x, ay*r*wv.y+bv.y, az*r*wv.z+bv.z, aw*r*wv.w+bv.w);
}

// ------- ALL weight transposes in ONE launch: fp32[K][N](ldw) -> bf16[N][K] -
struct WtD { const float* W; u16* Wt; int ldw, K, kb, nt; };
struct WtTab { WtD d[15]; };

__global__ __launch_bounds__(256) void wtall_k(WtTab tab)
{
  int loc = blockIdx.x;
  int r = 0;
#pragma unroll
  for (int i=0;i<15;i++){
    int cnt = tab.d[i].kb * tab.d[i].nt;
    if (loc >= cnt && r == i){ loc -= cnt; r = i+1; }
  }
  const float* W = tab.d[r].W;
  u16* Wt = tab.d[r].Wt;
  int ldw = tab.d[r].ldw, K = tab.d[r].K, kb = tab.d[r].kb;
  int k0 = (loc % kb)*32, n0 = (loc / kb)*32;
  __shared__ float tl[32][33];
  int t = threadIdx.x; int ty=t>>5, tx=t&31;
#pragma unroll
  for (int i=0;i<4;i++){
    int k = ty + i*8;
    tl[k][tx] = W[(size_t)(k0+k)*ldw + n0+tx];
  }
  __syncthreads();
#pragma unroll
  for (int i=0;i<4;i++){
    int n = ty + i*8;
    Wt[(size_t)(n0+n)*K + k0 + tx] = f2b(tl[tx][n]);
  }
}

enum { EPI_NONE=0, EPI_SILU=1, EPI_GELU=2, EPI_SIGMUL=3, EPI_ADD=4, EPI_RELU=5, EPI_SIGMOID=6 };

// -------- MFMA GEMM: out[M,N] = epi(cat(A1,A2)[M,K] @ Wt[N,K]^T + bias) ----
// XCD-aware swizzle; swapped MFMA operands (D^T layout) so each lane owns
// 4 consecutive output columns -> vector stores in the epilogue.
template<int BM, int BN, int EPI, bool WIN, bool WINST, typename OT, typename CT>
__global__ __launch_bounds__(256) void mgemm_k(
    const u16* __restrict__ A1, const u16* __restrict__ A2, int K1, int K2,
    const u16* __restrict__ Wt, const float* __restrict__ bias,
    const OT* other, CT* outp, int N, int r0)
{
  constexpr int MW = BM/32;
  constexpr int NWF = BN/32;
  constexpr int LA = BM/32;
  constexpr int LB = BN/32;
  __shared__ u16 As[BM][64];
  __shared__ u16 Bs[BN][64];
  int bx, by;
  xcdswz(blockIdx.y*gridDim.x + blockIdx.x, gridDim.x*gridDim.y, gridDim.x, bx, by);
  int m0 = by*BM, n0 = bx*BN;
  int t = threadIdx.x;
  int lane = t&63, w = t>>6;
  int wr = w>>1, wc = w&1;
  int K = K1 + K2;
  f32x4 acc[MW][NWF];
#pragma unroll
  for (int mi=0;mi<MW;mi++)
#pragma unroll
    for (int ni=0;ni<NWF;ni++) acc[mi][ni] = (f32x4){0.f,0.f,0.f,0.f};
  int srow = lane>>3;
  int cs   = ((lane&7) ^ srow)*8;
  size_t aoff1[LA], aoff2[LA];
#pragma unroll
  for (int i=0;i<LA;i++){
    int gr = m0 + i*32 + w*8 + srow;
    if (WIN) aoff1[i] = (size_t)winmap_tok(r0+gr)*K1;
    else { aoff1[i] = (size_t)gr*K1; aoff2[i] = (size_t)gr*K2; }
  }
  size_t boff[LB];
#pragma unroll
  for (int i=0;i<LB;i++)
    boff[i] = (size_t)(n0 + i*32 + w*8 + srow)*K;
  for (int k0=0; k0<K; k0+=64){
#pragma unroll
    for (int i=0;i<LA;i++){
      const u16* ap = (WIN || k0 < K1) ? A1 + aoff1[i] + k0 + cs
                                       : A2 + aoff2[i] + (k0-K1) + cs;
      gl16(ap, &As[i*32 + w*8][0]);
    }
#pragma unroll
    for (int i=0;i<LB;i++){
      gl16(Wt + boff[i] + k0 + cs, &Bs[i*32 + w*8][0]);
    }
    __syncthreads();
    int lg = lane>>4, li = lane&15;
#pragma unroll
    for (int kk=0;kk<2;kk++){
      s16x8 afr[MW], bfr[NWF];
#pragma unroll
      for (int mi=0;mi<MW;mi++){
        int lr = wr*(BM/2)+mi*16+li;
        afr[mi] = *(const s16x8*)&As[lr][(((kk<<2)+lg) ^ (lr&7))<<3];
      }
#pragma unroll
      for (int ni=0;ni<NWF;ni++){
        int lr = wc*(BN/2)+ni*16+li;
        bfr[ni] = *(const s16x8*)&Bs[lr][(((kk<<2)+lg) ^ (lr&7))<<3];
      }
#pragma unroll
      for (int mi=0;mi<MW;mi++)
#pragma unroll
        for (int ni=0;ni<NWF;ni++)
          acc[mi][ni] = __builtin_amdgcn_mfma_f32_16x16x32_bf16(bfr[ni], afr[mi], acc[mi][ni], 0,0,0);
    }
    __syncthreads();
  }
  int lg = lane>>4, li = lane&15;
#pragma unroll
  for (int mi=0;mi<MW;mi++){
    int gm = m0 + wr*(BM/2) + mi*16 + li;
    size_t orow = WINST ? (size_t)winmap_tok(r0+gm) : (size_t)gm;
#pragma unroll
    for (int ni=0;ni<NWF;ni++){
      int gnb = n0 + wc*(BN/2) + ni*16 + lg*4;
      float4 bv = bias ? *(const float4*)(bias+gnb) : make_float4(0.f,0.f,0.f,0.f);
      size_t off = orow*N + gnb;
      float v0 = acc[mi][ni][0] + bv.x;
      float v1 = acc[mi][ni][1] + bv.y;
      float v2 = acc[mi][ni][2] + bv.z;
      float v3 = acc[mi][ni][3] + bv.w;
      if (EPI==EPI_SILU){ v0=silu_(v0); v1=silu_(v1); v2=silu_(v2); v3=silu_(v3); }
      else if (EPI==EPI_GELU){ v0=gelu_(v0); v1=gelu_(v1); v2=gelu_(v2); v3=gelu_(v3); }
      else if (EPI==EPI_RELU){ v0=fmaxf(v0,0.f); v1=fmaxf(v1,0.f); v2=fmaxf(v2,0.f); v3=fmaxf(v3,0.f); }
      else if (EPI==EPI_SIGMOID){ v0=sigm_(v0); v1=sigm_(v1); v2=sigm_(v2); v3=sigm_(v3); }
      else if (EPI==EPI_SIGMUL){
        float4 o = ld4(other + off);
        v0 = o.x*sigm_(v0); v1 = o.y*sigm_(v1); v2 = o.z*sigm_(v2); v3 = o.w*sigm_(v3);
      }
      else if (EPI==EPI_ADD){
        float4 o = ld4(other + off);
        v0 += o.x; v1 += o.y; v2 += o.z; v3 += o.w;
      }
      st4(outp + off, v0, v1, v2, v3);
    }
  }
}

// -------- fp32 fallback GEMM (tiny N): out = epi(A[M,K]@W[K,N]+bias) -------
template<int EPI, typename OT, typename CT>
__global__ __launch_bounds__(256) void gemm_k(
    const u16* __restrict__ A1, const u16* __restrict__ A2, int K1, int K2,
    const float* __restrict__ W, int ldw, const float* __restrict__ bias,
    const OT* other, CT* outp, int M, int N)
{
  __shared__ float as[16][68];
  __shared__ float bs[16][64];
  int m0 = blockIdx.y*64, n0 = blockIdx.x*64;
  int t = threadIdx.x;
  int ty = t>>4, tx = t&15;
  float acc[4][4] = {{0.f}};
  int K = K1 + K2;
  int arow = t>>2, ac4 = (t&3)<<2;
  int bkr = t>>4, bnc = (t&15)<<2;
  for (int k0=0; k0<K; k0+=16){
    int gk = k0 + ac4;
    float4 av;
    if (gk < K1) av = ld4(A1 + (size_t)(m0+arow)*K1 + gk);
    else         av = ld4(A2 + (size_t)(m0+arow)*K2 + (gk-K1));
    as[ac4+0][arow]=av.x; as[ac4+1][arow]=av.y; as[ac4+2][arow]=av.z; as[ac4+3][arow]=av.w;
    int gn = n0 + bnc;
    const float* wp = W + (size_t)(k0+bkr)*ldw;
    if (gn+3 < N) {
      *(float4*)&bs[bkr][bnc] = *(const float4*)(wp + gn);
    } else {
#pragma unroll
      for (int j=0;j<4;j++) bs[bkr][bnc+j] = (gn+j<N) ? wp[gn+j] : 0.f;
    }
    __syncthreads();
#pragma unroll
    for (int kk=0; kk<16; kk++){
      float4 a4 = *(const float4*)&as[kk][ty*4];
      float4 b4 = *(const float4*)&bs[kk][tx*4];
      acc[0][0]+=a4.x*b4.x; acc[0][1]+=a4.x*b4.y; acc[0][2]+=a4.x*b4.z; acc[0][3]+=a4.x*b4.w;
      acc[1][0]+=a4.y*b4.x; acc[1][1]+=a4.y*b4.y; acc[1][2]+=a4.y*b4.z; acc[1][3]+=a4.y*b4.w;
      acc[2][0]+=a4.z*b4.x; acc[2][1]+=a4.z*b4.y; acc[2][2]+=a4.z*b4.z; acc[2][3]+=a4.z*b4.w;
      acc[3][0]+=a4.w*b4.x; acc[3][1]+=a4.w*b4.y; acc[3][2]+=a4.w*b4.z; acc[3][3]+=a4.w*b4.w;
    }
    __syncthreads();
  }
#pragma unroll
  for (int i=0;i<4;i++){
    int gm = m0 + ty*4 + i;
#pragma unroll
    for (int j=0;j<4;j++){
      int gn = n0 + tx*4 + j;
      if (gn >= N) continue;
      float v = acc[i][j] + (bias ? bias[gn] : 0.f);
      size_t off = (size_t)gm*N + gn;
      if (EPI==EPI_SILU)        v = silu_(v);
      else if (EPI==EPI_GELU)   v = gelu_(v);
      else if (EPI==EPI_SIGMUL) v = tof(other[off])*sigm_(v);
      else if (EPI==EPI_ADD)    v = v + tof(other[off]);
      else if (EPI==EPI_RELU)   v = fmaxf(v,0.f);
      else if (EPI==EPI_SIGMOID)v = sigm_(v);
      sto(outp + off, v);
    }
  }
}

// ---- fused xBC GEMM (M=64 tile) + causal conv(4) + SiLU -> XC2/XT ---------
// XCD-aware swizzle; swapped MFMA operands -> float4 LDS writes into Cls.
__global__ __launch_bounds__(256) void xbcconv_k(
    const u16* __restrict__ A1, const u16* __restrict__ Wt,
    const float* __restrict__ cw, const float* __restrict__ cb,
    u16* __restrict__ XC, u16* __restrict__ XT)
{
  __shared__ u16 As[64][40];
  __shared__ u16 Ab[16][40];
  __shared__ u16 Bs[128][40];
  __shared__ float Cls[67][132];
  int bx, by;
  xcdswz(blockIdx.y*gridDim.x + blockIdx.x, gridDim.x*gridDim.y, gridDim.x, bx, by);
  int m0 = by*64, n0 = bx*128;
  bool first = ((m0 & 4095) == 0);
  int t = threadIdx.x;
  int lane = t&63, w = t>>6;
  int wr = w>>1, wc = w&1;
  int lg = lane>>4, li = lane&15;
  f32x4 acc[2][4], acc3[2];
#pragma unroll
  for (int mi=0;mi<2;mi++)
#pragma unroll
    for (int ni=0;ni<4;ni++) acc[mi][ni] = (f32x4){0.f,0.f,0.f,0.f};
  acc3[0]=(f32x4){0,0,0,0}; acc3[1]=(f32x4){0,0,0,0};
  for (int i=t; i<320; i+=256) ((u32*)&Ab[0][0])[i] = 0u;
  int lrow = t>>2, lc8 = (t&3)*8;
  for (int k0=0; k0<256; k0+=32){
    *(uint4*)&As[lrow][lc8] = *(const uint4*)(A1 + (size_t)(m0+lrow)*256 + k0 + lc8);
    if (t < 12 && !first){
      int r3 = t>>2, seg = t&3;
      *(uint4*)&Ab[r3][seg*8] = *(const uint4*)(A1 + (size_t)(m0-3+r3)*256 + k0 + seg*8);
    }
#pragma unroll
    for (int i=0;i<2;i++){
      int row = lrow + i*64;
      *(uint4*)&Bs[row][lc8] = *(const uint4*)(Wt + (size_t)(n0+row)*256 + k0 + lc8);
    }
    __syncthreads();
    s16x8 afr[2], bfr[4];
#pragma unroll
    for (int mi=0;mi<2;mi++)
      afr[mi] = *(const s16x8*)&As[wr*32+mi*16+li][lg*8];
#pragma unroll
    for (int ni=0;ni<4;ni++)
      bfr[ni] = *(const s16x8*)&Bs[wc*64+ni*16+li][lg*8];
#pragma unroll
    for (int mi=0;mi<2;mi++)
#pragma unroll
      for (int ni=0;ni<4;ni++)
        acc[mi][ni] = __builtin_amdgcn_mfma_f32_16x16x32_bf16(bfr[ni], afr[mi], acc[mi][ni], 0,0,0);
    {
      s16x8 abf = *(const s16x8*)&Ab[li][lg*8];
#pragma unroll
      for (int ni2=0;ni2<2;ni2++){
        s16x8 bb = *(const s16x8*)&Bs[w*32+ni2*16+li][lg*8];
        acc3[ni2] = __builtin_amdgcn_mfma_f32_16x16x32_bf16(bb, abf, acc3[ni2], 0,0,0);
      }
    }
    __syncthreads();
  }
#pragma unroll
  for (int mi=0;mi<2;mi++){
    int rl = wr*32 + mi*16 + li;
#pragma unroll
    for (int ni=0;ni<4;ni++){
      int colb = wc*64 + ni*16 + lg*4;
      *(f32x4*)&Cls[3+rl][colb] = acc[mi][ni];
    }
  }
  if (li < 3){
#pragma unroll
    for (int ni2=0;ni2<2;ni2++){
      int colb = w*32 + ni2*16 + lg*4;
      *(f32x4*)&Cls[li][colb] = acc3[ni2];
    }
  }
  __syncthreads();
  int col = t & 127, half = t >> 7;
  int ch = n0 + col;
  float w0 = cw[ch*4+0], w1 = cw[ch*4+1], w2 = cw[ch*4+2], w3 = cw[ch*4+3];
  float bias = cb[ch];
  int r0 = half*32;
  float c0 = Cls[r0+0][col], c1 = Cls[r0+1][col], c2 = Cls[r0+2][col];
  u16 xtbuf[32];
  if (ch < 512){
#pragma unroll
    for (int rr=0; rr<32; rr++){
      float c3 = Cls[r0+rr+3][col];
      float v = bias + w0*c0 + w1*c1 + w2*c2 + w3*c3;
      xtbuf[rr] = f2b(silu_(v));
      c0=c1; c1=c2; c2=c3;
    }
    int g = m0 >> 8;
    u16* dst = XT + ((size_t)(g*512 + ch))*256 + (m0&255) + r0;
#pragma unroll
    for (int q=0;q<4;q++) *(uint4*)(dst + q*8) = *(const uint4*)&xtbuf[q*8];
  } else {
#pragma unroll
    for (int rr=0; rr<32; rr++){
      float c3 = Cls[r0+rr+3][col];
      float v = bias + w0*c0 + w1*c1 + w2*c2 + w3*c3;
      XC[(size_t)(m0 + r0 + rr)*128 + (ch-512)] = f2b(silu_(v));
      c0=c1; c1=c2; c2=c3;
    }
  }
}

// ----- dt softplus fused into per-chunk cumsum (writes DT and ACS) ---------
__global__ __launch_bounds__(256) void acs_k(
    const float* __restrict__ DTRAW, const float* __restrict__ dtb, const float* __restrict__ alog,
    float* __restrict__ DT_, float* __restrict__ ACS_)
{
  int wid = (blockIdx.x<<2) + (threadIdx.x>>6);
  int lane = threadIdx.x & 63;
  int c  = wid & 15;
  int bh = wid >> 4;
  int b  = bh >> 3, h = bh & 7;
  float db = dtb[h];
  float ea = __expf(alog[h]);
  size_t tok0 = (size_t)b*4096 + c*256 + lane*4;
  float v0,v1,v2,v3;
  {
    float xv, sp;
    xv = DTRAW[(tok0+0)*8 + h] + db; sp = (xv>20.f)?xv:log1pf(__expf(xv)); DT_[(tok0+0)*8+h]=sp; v0 = -sp*ea;
    xv = DTRAW[(tok0+1)*8 + h] + db; sp = (xv>20.f)?xv:log1pf(__expf(xv)); DT_[(tok0+1)*8+h]=sp; v1 = -sp*ea;
    xv = DTRAW[(tok0+2)*8 + h] + db; sp = (xv>20.f)?xv:log1pf(__expf(xv)); DT_[(tok0+2)*8+h]=sp; v2 = -sp*ea;
    xv = DTRAW[(tok0+3)*8 + h] + db; sp = (xv>20.f)?xv:log1pf(__expf(xv)); DT_[(tok0+3)*8+h]=sp; v3 = -sp*ea;
  }
  v1 += v0; v2 += v1; v3 += v2;
  float tot = v3, s = tot;
#pragma unroll
  for (int o=1;o<64;o<<=1){
    float u = __shfl_up(s, o, 64);
    if (lane >= o) s += u;
  }
  float excl = s - tot;
  float* dst = ACS_ + (size_t)bh*4096 + c*256 + lane*4;
  dst[0]=excl+v0; dst[1]=excl+v1; dst[2]=excl+v2; dst[3]=excl+v3;
}

// ------- chunk end-states via MFMA; Xt from XT; B from XC2; XCD-affinity ---
__global__ __launch_bounds__(256) void states_k(
    const u16* __restrict__ XC, const u16* __restrict__ XT,
    const float* __restrict__ DTc, const float* __restrict__ ACSc,
    float* __restrict__ ST)
{
  int b = blockIdx.x;
  int j = b & 7, s = b >> 3;
  int h = s & 7, gq = s >> 3;
  int g = j + gq*8;                 // g = bl*16 + c
  int c = g & 15, bl = g >> 4;
  __shared__ u16 Xt[64*64];
  __shared__ u16 Bt[64*64];
  int t = threadIdx.x;
  int lane = t&63, w = t>>6;
  int wr = w>>1, wc = w&1;
  int lg = lane>>4, li = lane&15;
  const float* acs = ACSc + ((size_t)(bl*8+h))*4096 + c*256;
  float aL = acs[255];
  size_t tok0 = (size_t)bl*4096 + c*256;
  f32x4 acc[2][2];
#pragma unroll
  for (int mi=0;mi<2;mi++)
#pragma unroll
    for (int ni=0;ni<2;ni++) acc[mi][ni] = (f32x4){0.f,0.f,0.f,0.f};
  int sr = t>>2, cg = t&3;
  int srch = sr>>3, srlo = sr&7;
  const u16* xtb = XT + ((size_t)(g*512) + h*64)*256;
  for (int s0=0; s0<256; s0+=64){
    __syncthreads();
    {
      int prow = t>>2, c2 = t&3;
      const u16* src = xtb + (size_t)prow*256 + s0;
      uint4 a0 = *(const uint4*)(src + c2*8);
      uint4 a1 = *(const uint4*)(src + (c2+4)*8);
      *(uint4*)&Xt[prow*64 + (vswz(prow,c2)<<3)]   = a0;
      *(uint4*)&Xt[prow*64 + (vswz(prow,c2+4)<<3)] = a1;
    }
    {
      size_t grow = tok0 + s0 + sr;
      float scl = __expf(aL - acs[s0+sr]) * DTc[grow*8 + h];
      const u16* brow_p = XC + grow*128 + cg*16;
      uint4 ba = *(const uint4*)brow_p, bb2 = *(const uint4*)(brow_p+8);
      const u16* bu = (const u16*)&ba;
#pragma unroll
      for (int jj=0;jj<8;jj++){
        int row = cg*16+jj;
        Bt[row*64 + (vswz(row,srch)<<3) + srlo] = f2b(b2f(bu[jj])*scl);
      }
      const u16* bu2 = (const u16*)&bb2;
#pragma unroll
      for (int jj=0;jj<8;jj++){
        int row = cg*16+8+jj;
        Bt[row*64 + (vswz(row,srch)<<3) + srlo] = f2b(b2f(bu2[jj])*scl);
      }
    }
    __syncthreads();
    s16x8 afr[2][2], bfr[2][2];
#pragma unroll
    for (int kk=0;kk<2;kk++){
#pragma unroll
      for (int mi=0;mi<2;mi++){
        int row = wr*32+mi*16+li;
        afr[mi][kk] = *(const s16x8*)&Xt[row*64 + (vswz(row, kk*4+lg)<<3)];
      }
#pragma unroll
      for (int ni=0;ni<2;ni++){
        int row = wc*32+ni*16+li;
        bfr[ni][kk] = *(const s16x8*)&Bt[row*64 + (vswz(row, kk*4+lg)<<3)];
      }
    }
#pragma unroll
    for (int kk=0;kk<2;kk++)
#pragma unroll
      for (int mi=0;mi<2;mi++)
#pragma unroll
        for (int ni=0;ni<2;ni++)
          acc[mi][ni] = __builtin_amdgcn_mfma_f32_16x16x32_bf16(afr[mi][kk], bfr[ni][kk], acc[mi][ni], 0,0,0);
  }
  float* dst = ST + ((size_t)(g*8 + h))*4096;
#pragma unroll
  for (int mi=0;mi<2;mi++)
#pragma unroll
    for (int ni=0;ni<2;ni++){
      int gn = wc*32 + ni*16 + li;
#pragma unroll
      for (int r=0;r<4;r++){
        int gp = wr*32 + mi*16 + lg*4 + r;
        dst[gp*64 + gn] = acc[mi][ni][r];
      }
    }
}

// ------- sequential inter-chunk scan; STIN out bf16; split over e ----------
__global__ __launch_bounds__(256) void scan_k(
    const float* __restrict__ ST, const float* __restrict__ ACSc, u16* __restrict__ STIN)
{
  int bid = blockIdx.x;              // (bl*8+h)*4 + eq
  int eq = bid & 3, h = (bid>>2)&7, bl = bid>>5;
  int t = threadIdx.x;
  float hr[4] = {0.f,0.f,0.f,0.f};
  for (int c=0;c<16;c++){
    float dec = __expf(ACSc[((size_t)(bl*8+h))*4096 + c*256 + 255]);
    size_t base = ((size_t)((bl*16+c)*8+h))*4096 + (size_t)eq*1024;
#pragma unroll
    for (int e=0;e<4;e++){
      size_t idx = base + e*256 + t;
      float st = ST[idx];
      STIN[idx] = f2b(hr[e]);
      hr[e] = hr[e]*dec + st;
    }
  }
}

// ------------ Y = Yd + Yo + d_skip*xs via MFMA; head-pair blocks -----------
__global__ __launch_bounds__(256) void ydy_k(
    const u16* __restrict__ XC, const u16* __restrict__ XT,
    const float* __restrict__ DTc,
    const float* __restrict__ ACSc, const u16* __restrict__ STIN,
    const float* __restrict__ dskip, u16* __restrict__ Y)
{
  int b = blockIdx.x;
  int j = b & 7, s = b >> 3;
  int hp = s & 3, ltp = (s>>2) & 1, gq = s >> 3;
  int g = j + gq*8;                 // g = bl*16 + c
  int c = g & 15, bl = g >> 4;
  int h0 = hp*2, h1 = h0 + 1;
  __shared__ u16 Ct[64][72];
  __shared__ u16 Sb[64][72];
  __shared__ u16 Sl[64][72];
  __shared__ u16 Vt0[64*64];
  __shared__ u16 Vt1[64*64];
  int t = threadIdx.x;
  int lane = t&63, w = t>>6;
  int wr = w>>1, wc = w&1;
  int lg = lane>>4, li = lane&15;
  const float* acs0 = ACSc + ((size_t)(bl*8+h0))*4096 + c*256;
  const float* acs1 = ACSc + ((size_t)(bl*8+h1))*4096 + c*256;
  size_t tok0 = (size_t)bl*4096 + c*256;
  int sr = t>>2;
  const u16* stin0 = STIN + ((size_t)(g*8+h0))*4096;
  const u16* stin1 = STIN + ((size_t)(g*8+h1))*4096;
  const u16* xtb0 = XT + ((size_t)(g*512) + h0*64)*256;
  const u16* xtb1 = XT + ((size_t)(g*512) + h1*64)*256;
  float dsk0 = dskip[h0], dsk1 = dskip[h1];
  for (int pp=0; pp<2; pp++){
    int lt = pp ? (3-ltp) : ltp;
    int l0 = lt*64;
#pragma unroll
    for (int it=0; it<2; it++){
      int seg = (t&3) + it*4;
      *(uint4*)&Ct[sr][seg*8] = *(const uint4*)(XC + (tok0+l0+sr)*128 + 64 + seg*8);
    }
    float acsl0[2][4], acsl1[2][4];
#pragma unroll
    for (int mi=0;mi<2;mi++)
#pragma unroll
      for (int r=0;r<4;r++){
        int idx = l0 + wr*32 + mi*16 + lg*4 + r;
        acsl0[mi][r] = acs0[idx];
        acsl1[mi][r] = acs1[idx];
      }
    f32x4 accP0[2][2], accP1[2][2];
    __syncthreads();
    // Yo (head0) -> accP0 init
    {
      f32x4 aO[2][2];
#pragma unroll
      for (int mi=0;mi<2;mi++)
#pragma unroll
        for (int ni=0;ni<2;ni++) aO[mi][ni]=(f32x4){0,0,0,0};
#pragma unroll
      for (int kk=0;kk<2;kk++){
        s16x8 bfr[2];
#pragma unroll
        for (int ni=0;ni<2;ni++){
          int p = wc*32 + ni*16 + li;
          bfr[ni] = *(const s16x8*)(stin0 + p*64 + kk*32 + lg*8);
        }
#pragma unroll
        for (int mi=0;mi<2;mi++){
          s16x8 afr = *(const s16x8*)&Ct[wr*32+mi*16+li][kk*32+lg*8];
#pragma unroll
          for (int ni=0;ni<2;ni++)
            aO[mi][ni] = __builtin_amdgcn_mfma_f32_16x16x32_bf16(afr, bfr[ni], aO[mi][ni], 0,0,0);
        }
      }
#pragma unroll
      for (int mi=0;mi<2;mi++)
#pragma unroll
        for (int ni=0;ni<2;ni++)
#pragma unroll
          for (int r=0;r<4;r++)
            accP0[mi][ni][r] = __expf(acsl0[mi][r]) * aO[mi][ni][r];
    }
    // Yo (head1) -> accP1 init
    {
      f32x4 aO[2][2];
#pragma unroll
      for (int mi=0;mi<2;mi++)
#pragma unroll
        for (int ni=0;ni<2;ni++) aO[mi][ni]=(f32x4){0,0,0,0};
#pragma unroll
      for (int kk=0;kk<2;kk++){
        s16x8 bfr[2];
#pragma unroll
        for (int ni=0;ni<2;ni++){
          int p = wc*32 + ni*16 + li;
          bfr[ni] = *(const s16x8*)(stin1 + p*64 + kk*32 + lg*8);
        }
#pragma unroll
        for (int mi=0;mi<2;mi++){
          s16x8 afr = *(const s16x8*)&Ct[wr*32+mi*16+li][kk*32+lg*8];
#pragma unroll
          for (int ni=0;ni<2;ni++)
            aO[mi][ni] = __builtin_amdgcn_mfma_f32_16x16x32_bf16(afr, bfr[ni], aO[mi][ni], 0,0,0);
        }
      }
#pragma unroll
      for (int mi=0;mi<2;mi++)
#pragma unroll
        for (int ni=0;ni<2;ni++)
#pragma unroll
          for (int r=0;r<4;r++)
            accP1[mi][ni][r] = __expf(acsl1[mi][r]) * aO[mi][ni][r];
    }
    for (int sb=0; sb<=lt; sb++){
      int s0 = sb*64;
      // stage B (shared) + V for both heads
#pragma unroll
      for (int it=0; it<2; it++){
        int seg = (t&3) + it*4;
        *(uint4*)&Sb[sr][seg*8] = *(const uint4*)(XC + (tok0+s0+sr)*128 + seg*8);
      }
      {
        int prow = t>>2, c2 = t&3;
        const u16* src0 = xtb0 + (size_t)prow*256 + s0;
        uint4 a0 = *(const uint4*)(src0 + c2*8);
        uint4 a1 = *(const uint4*)(src0 + (c2+4)*8);
        *(uint4*)&Vt0[prow*64 + (vswz(prow,c2)<<3)]   = a0;
        *(uint4*)&Vt0[prow*64 + (vswz(prow,c2+4)<<3)] = a1;
        const u16* src1 = xtb1 + (size_t)prow*256 + s0;
        uint4 b0 = *(const uint4*)(src1 + c2*8);
        uint4 b1 = *(const uint4*)(src1 + (c2+4)*8);
        *(uint4*)&Vt1[prow*64 + (vswz(prow,c2)<<3)]   = b0;
        *(uint4*)&Vt1[prow*64 + (vswz(prow,c2+4)<<3)] = b1;
      }
      __syncthreads();
      // shared S = C_l * B_s^T
      f32x4 sacc[2][2];
#pragma unroll
      for (int mi=0;mi<2;mi++)
#pragma unroll
        for (int ni=0;ni<2;ni++) sacc[mi][ni]=(f32x4){0,0,0,0};
#pragma unroll
      for (int kk=0;kk<2;kk++){
        s16x8 bfr[2];
#pragma unroll
        for (int ni=0;ni<2;ni++)
          bfr[ni] = *(const s16x8*)&Sb[wc*32+ni*16+li][kk*32+lg*8];
#pragma unroll
        for (int mi=0;mi<2;mi++){
          s16x8 afr = *(const s16x8*)&Ct[wr*32+mi*16+li][kk*32+lg*8];
#pragma unroll
          for (int ni=0;ni<2;ni++)
            sacc[mi][ni] = __builtin_amdgcn_mfma_f32_16x16x32_bf16(afr, bfr[ni], sacc[mi][ni], 0,0,0);
        }
      }
      // ---- head 0: P -> Sl, PV ----
#pragma unroll
      for (int ni=0;ni<2;ni++){
        int cs2 = wc*32 + ni*16 + li;
        int gsj = s0 + cs2;
        float acss = acs0[gsj];
        float dts = DTc[(tok0+gsj)*8 + h0];
#pragma unroll
        for (int mi=0;mi<2;mi++){
#pragma unroll
          for (int r=0;r<4;r++){
            int lrow = wr*32 + mi*16 + lg*4 + r;
            int gl = l0 + lrow;
            float wgt = (gsj <= gl) ? __expf(acsl0[mi][r] - acss)*dts : 0.f;
            Sl[lrow][cs2] = f2b(sacc[mi][ni][r] * wgt);
          }
        }
      }
      __syncthreads();
#pragma unroll
      for (int kk=0;kk<2;kk++){
        s16x8 bfr[2];
#pragma unroll
        for (int ni=0;ni<2;ni++){
          int p = wc*32+ni*16+li;
          bfr[ni] = *(const s16x8*)&Vt0[p*64 + (vswz(p, kk*4+lg)<<3)];
        }
#pragma unroll
        for (int mi=0;mi<2;mi++){
          s16x8 afr = *(const s16x8*)&Sl[wr*32+mi*16+li][kk*32+lg*8];
#pragma unroll
          for (int ni=0;ni<2;ni++)
            accP0[mi][ni] = __builtin_amdgcn_mfma_f32_16x16x32_bf16(afr, bfr[ni], accP0[mi][ni], 0,0,0);
        }
      }
      __syncthreads();
      // ---- head 1: P -> Sl, PV ----
#pragma unroll
      for (int ni=0;ni<2;ni++){
        int cs2 = wc*32 + ni*16 + li;
        int gsj = s0 + cs2;
        float acss = acs1[gsj];
        float dts = DTc[(tok0+gsj)*8 + h1];
#pragma unroll
        for (int mi=0;mi<2;mi++){
#pragma unroll
          for (int r=0;r<4;r++){
            int lrow = wr*32 + mi*16 + lg*4 + r;
            int gl = l0 + lrow;
            float wgt = (gsj <= gl) ? __expf(acsl1[mi][r] - acss)*dts : 0.f;
            Sl[lrow][cs2] = f2b(sacc[mi][ni][r] * wgt);
          }
        }
      }
      __syncthreads();
#pragma unroll
      for (int kk=0;kk<2;kk++){
        s16x8 bfr[2];
#pragma unroll
        for (int ni=0;ni<2;ni++){
          int p = wc*32+ni*16+li;
          bfr[ni] = *(const s16x8*)&Vt1[p*64 + (vswz(p, kk*4+lg)<<3)];
        }
#pragma unroll
        for (int mi=0;mi<2;mi++){
          s16x8 afr = *(const s16x8*)&Sl[wr*32+mi*16+li][kk*32+lg*8];
#pragma unroll
          for (int ni=0;ni<2;ni++)
            accP1[mi][ni] = __builtin_amdgcn_mfma_f32_16x16x32_bf16(afr, bfr[ni], accP1[mi][ni], 0,0,0);
        }
      }
      __syncthreads();
    }
    // epilogue: out(h0) -> Sb, out(h1) -> Ct, then store both
#pragma unroll
    for (int mi=0;mi<2;mi++){
#pragma unroll
      for (int ni=0;ni<2;ni++){
        int p = wc*32 + ni*16 + li;
#pragma unroll
        for (int r=0;r<4;r++){
          int lrow = wr*32 + mi*16 + lg*4 + r;
          int voff = p*64 + (vswz(p, lrow>>3)<<3) + (lrow&7);
          float xsv0 = b2f(Vt0[voff]);
          float xsv1 = b2f(Vt1[voff]);
          Sb[lrow][p] = f2b(accP0[mi][ni][r] + dsk0*xsv0);
          Ct[lrow][p] = f2b(accP1[mi][ni][r] + dsk1*xsv1);
        }
      }
    }
    __syncthreads();
#pragma unroll
    for (int it=0; it<2; it++){
      int seg = (t&3) + it*4;
      *(uint4*)(Y + (tok0+l0+sr)*512 + h0*64 + seg*8) = *(const uint4*)&Sb[sr][seg*8];
      *(uint4*)(Y + (tok0+l0+sr)*512 + h1*64 + seg*8) = *(const uint4*)&Ct[sr][seg*8];
    }
    __syncthreads();
  }
}

// ---------------- u = y*silu(z); RMSNorm*w over 512 (in place) -------------
__global__ __launch_bounds__(256) void urms_k(
    u16* Y, const u16* __restrict__ Z, const float* __restrict__ nw)
{
  int tok = blockIdx.x*4 + (threadIdx.x>>6);
  int lane = threadIdx.x & 63;
  size_t base = (size_t)tok*512 + lane*8;
  float y[8], z[8], u[8];
  ld8(Y+base, y); ld8(Z+base, z);
  float ss=0.f;
#pragma unroll
  for (int e=0;e<8;e++){ u[e] = y[e]*silu_(z[e]); ss += u[e]*u[e]; }
  ss = wsum_(ss);
  float r = rsqrtf(ss*(1.f/512.f) + 1e-5f);
  float4 w0 = *(const float4*)(nw + lane*8);
  float4 w1 = *(const float4*)(nw + lane*8 + 4);
  float o[8];
  o[0]=u[0]*r*w0.x; o[1]=u[1]*r*w0.y; o[2]=u[2]*r*w0.z; o[3]=u[3]*r*w0.w;
  o[4]=u[4]*r*w1.x; o[5]=u[5]*r*w1.y; o[6]=u[6]*r*w1.z; o[7]=u[7]*r*w1.w;
  st8(Y+base, o);
}

// ------------ window attention via MFMA, block per (window, head) ----------
__global__ __launch_bounds__(256) void attn_k(
    const u16* __restrict__ QKV, const float* __restrict__ rpb, u16* __restrict__ OW)
{
  int win = blockIdx.x;
  int wid = win & 63;
  int head = blockIdx.y;
  __shared__ u16 Qs[64][40];
  __shared__ u16 Ks[64][40];
  __shared__ u16 Vt[32][72];
  __shared__ u16 Pl[64][72];
  __shared__ float rl[225];
  __shared__ int rid[64];
  int t = threadIdx.x;
  int lane = t&63, w = t>>6;
  int lg = lane>>4, li = lane&15;
  const float scale = 0.17677669529663687f;
  {
    int row = t>>2, seg = t&3;
    const u16* base = QKV + ((size_t)win*64 + row)*768 + head*32 + seg*8;
    uint4 q = *(const uint4*)base;
    const u16* qe = (const u16*)&q;
    u16 qs8[8];
#pragma unroll
    for (int jq=0;jq<8;jq++) qs8[jq] = f2b(b2f(qe[jq])*scale);
    *(uint4*)&Qs[row][seg*8] = *(const uint4*)qs8;
    *(uint4*)&Ks[row][seg*8] = *(const uint4*)(base + 256);
    uint4 v = *(const uint4*)(base + 512);
    const u16* ve = (const u16*)&v;
#pragma unroll
    for (int jq=0;jq<8;jq++) Vt[seg*8+jq][row] = ve[jq];
  }
  if (t < 225) rl[t] = rpb[t*8 + head];
  if (t < 64){
    int h2 = ((wid>>3)<<3) + (t>>3);
    int w2 = ((wid&7)<<3) + (t&7);
    int rh = (h2<56)?0:((h2<60)?1:2);
    int rw = (w2<56)?0:((w2<60)?1:2);
    rid[t] = rh*3 + rw;
  }
  __syncthreads();
  f32x4 sc[4];
  {
    s16x8 qf = *(const s16x8*)&Qs[w*16+li][lg*8];
#pragma unroll
    for (int ni=0;ni<4;ni++){
      s16x8 kf = *(const s16x8*)&Ks[ni*16+li][lg*8];
      sc[ni] = __builtin_amdgcn_mfma_f32_16x16x32_bf16(qf, kf, (f32x4){0,0,0,0}, 0,0,0);
    }
  }
  float inv[4];
#pragma unroll
  for (int r=0;r<4;r++){
    int i = w*16 + lg*4 + r;
    int ridi = rid[i];
    float vv[4];
    float m = -1e30f;
#pragma unroll
    for (int ni=0;ni<4;ni++){
      int jj = ni*16 + li;
      float sv = sc[ni][r] + rl[((i>>3)-(jj>>3)+7)*15 + ((i&7)-(jj&7)+7)];
      if (ridi != rid[jj]) sv -= 100.f;
      vv[ni] = sv;
      m = fmaxf(m, sv);
    }
#pragma unroll
    for (int o=1;o<16;o<<=1) m = fmaxf(m, __shfl_xor(m, o, 64));
    float sum = 0.f;
#pragma unroll
    for (int ni=0;ni<4;ni++){ vv[ni] = __expf(vv[ni]-m); sum += vv[ni]; }
#pragma unroll
    for (int o=1;o<16;o<<=1) sum += __shfl_xor(sum, o, 64);
    inv[r] = 1.f/sum;
#pragma unroll
    for (int ni=0;ni<4;ni++) Pl[i][ni*16+li] = f2b(vv[ni]);
  }
  __syncthreads();
  f32x4 oacc[2];
  oacc[0]=(f32x4){0,0,0,0}; oacc[1]=(f32x4){0,0,0,0};
#pragma unroll
  for (int kk=0;kk<2;kk++){
    s16x8 pf = *(const s16x8*)&Pl[w*16+li][kk*32+lg*8];
#pragma unroll
    for (int ni=0;ni<2;ni++){
      s16x8 vf = *(const s16x8*)&Vt[ni*16+li][kk*32+lg*8];
      oacc[ni] = __builtin_amdgcn_mfma_f32_16x16x32_bf16(pf, vf, oacc[ni], 0,0,0);
    }
  }
#pragma unroll
  for (int ni=0;ni<2;ni++)
#pragma unroll
    for (int r=0;r<4;r++)
      Pl[w*16+lg*4+r][ni*16+li] = f2b(oacc[ni][r]*inv[r]);
  __syncthreads();
  {
    int row = t>>2, seg = t&3;
    *(uint4*)(OW + ((size_t)win*64 + row)*256 + head*32 + seg*8) = *(const uint4*)&Pl[row][seg*8];
  }
}

// ---------------- host ------------------------------------------------------
extern "C" void kernel_launch(void* const* d_in, const int* in_sizes, int n_in,
                              void* d_out, int out_size, void* d_ws, size_t ws_size,
                              hipStream_t stream)
{
  (void)in_sizes; (void)n_in; (void)out_size;
  const size_t OFF_XN   = 0;
  const size_t OFF_XNS  = 16777216;
  const size_t OFF_SP   = 33554432;
  const size_t OFF_DTRAW= 50331648;
  const size_t OFF_DT   = 51380224;
  const size_t OFF_ACS  = 53477376;
  const size_t OFF_WTS  = 54525952;
  const size_t ARO      = 58195968;
  int NB = 0;
  if      (ws_size >= ARO + 8ull*14680064) NB = 8;
  else if (ws_size >= ARO + 4ull*14680064) NB = 4;
  else if (ws_size >= ARO + 2ull*14680064) NB = 2;
  else if (ws_size >= ARO + 1ull*14680064) NB = 1;
  else return;
  int NC = 8 / NB;
  int RJ = (NB==8)?32768 : (NB==4)?16384 : (NB==2)?8192 : 4096;

  const float* x       = (const float*)d_in[0];
  const float* ln1_w   = (const float*)d_in[1];
  const float* ln1_b   = (const float*)d_in[2];
  const float* ns_w    = (const float*)d_in[3];
  const float* ns_b    = (const float*)d_in[4];
  const float* m_win   = (const float*)d_in[5];
  const float* m_conv_w= (const float*)d_in[6];
  const float* m_conv_b= (const float*)d_in[7];
  const float* m_dt_b  = (const float*)d_in[8];
  const float* m_a_log = (const float*)d_in[9];
  const float* m_d     = (const float*)d_in[10];
  const float* m_norm_w= (const float*)d_in[11];
  const float* m_wout  = (const float*)d_in[12];
  const float* tm_w1   = (const float*)d_in[13];
  const float* tm_b1   = (const float*)d_in[14];
  const float* tm_w2   = (const float*)d_in[15];
  const float* tm_b2   = (const float*)d_in[16];
  const float* nt_w    = (const float*)d_in[17];
  const float* nt_b    = (const float*)d_in[18];
  const float* qkv_w   = (const float*)d_in[19];
  const float* qkv_b   = (const float*)d_in[20];
  const float* rpb     = (const float*)d_in[21];
  const float* gate_w  = (const float*)d_in[22];
  const float* gate_b  = (const float*)d_in[23];
  const float* proj_w  = (const float*)d_in[24];
  const float* proj_b  = (const float*)d_in[25];
  const float* cg_w1a  = (const float*)d_in[26];
  const float* cg_b1a  = (const float*)d_in[27];
  const float* cg_w2a  = (const float*)d_in[28];
  const float* cg_b2a  = (const float*)d_in[29];
  const float* cg_w1m  = (const float*)d_in[30];
  const float* cg_b1m  = (const float*)d_in[31];
  const float* cg_w2m  = (const float*)d_in[32];
  const float* cg_b2m  = (const float*)d_in[33];
  const float* cg_wf   = (const float*)d_in[34];
  const float* cg_bf   = (const float*)d_in[35];
  const float* ln2_w   = (const float*)d_in[36];
  const float* ln2_b   = (const float*)d_in[37];
  const float* mlp_w1  = (const float*)d_in[38];
  const float* mlp_b1  = (const float*)d_in[39];
  const float* mlp_w2  = (const float*)d_in[40];
  const float* mlp_b2  = (const float*)d_in[41];
  float* dout = (float*)d_out;
  char* ws = (char*)d_ws;

  u16*  XN   = (u16*)(ws + OFF_XN);
  u16*  XNS  = (u16*)(ws + OFF_XNS);
  u16*  SP   = (u16*)(ws + OFF_SP);
  float* DTRAW = (float*)(ws + OFF_DTRAW);
  float* DT  = (float*)(ws + OFF_DT);
  float* ACS = (float*)(ws + OFF_ACS);
  u16*  WTS  = (u16*)(ws + OFF_WTS);
  u16* WT_XBC = WTS + 0;
  u16* WT_Z   = WTS + 163840;
  u16* WT_WOUT= WTS + 294912;
  u16* WT_TM1 = WTS + 425984;
  u16* WT_TM2 = WTS + 491520;
  u16* WT_QKV = WTS + 557056;
  u16* WT_GATE= WTS + 753664;
  u16* WT_PROJ= WTS + 819200;
  u16* WT_W2A = WTS + 884736;
  u16* WT_W2M = WTS + 901120;
  u16* WT_WF  = WTS + 917504;
  u16* WT_MLP1= WTS + 1048576;
  u16* WT_MLP2= WTS + 1310720;
  u16* WT_W1A = WTS + 1572864;
  u16* WT_W1M = WTS + 1589248;
  char* AR = ws + ARO;
  u16*  XCc   = (u16*)AR;
  u16*  Zc    = (u16*)(AR + (size_t)NB*5242880);
  u16*  XTc   = Zc;
  u16*  STINc = (u16*)(AR + (size_t)NB*9437184);
  float* STc  = (float*)(AR + (size_t)NB*10485760);
  u16*  Yc    = (u16*)(AR + (size_t)NB*10485760);
  u16*  QKVc  = (u16*)AR;
  u16*  OWc   = (u16*)(AR + (size_t)NB*6291456);
  u16*  TBUF  = (u16*)AR;
  u16*  XM    = XNS;
  u16*  XA    = XN;
  u16*  CGHA  = (u16*)AR;
  u16*  CGHM  = (u16*)(AR + 4194304);
  u16*  LNc   = (u16*)AR;
  u16*  MHc   = (u16*)(AR + (size_t)RJ*512);

  const size_t TB = 4096*256;
  const size_t H2 = 16384*256;

  // Phase 0: all weight transposes in one launch
  WtTab tab;
  tab.d[0]  = { m_win+512, WT_XBC, 1160, 256, 8, 20 };
  tab.d[1]  = { m_win,     WT_Z,   1160, 256, 8, 16 };
  tab.d[2]  = { m_wout,    WT_WOUT, 256, 512, 16, 8 };
  tab.d[3]  = { tm_w1,     WT_TM1,  256, 512, 16, 8 };
  tab.d[4]  = { tm_w2,     WT_TM2,  256, 256, 8, 8 };
  tab.d[5]  = { qkv_w,     WT_QKV,  768, 256, 8, 24 };
  tab.d[6]  = { gate_w,    WT_GATE, 256, 256, 8, 8 };
  tab.d[7]  = { proj_w,    WT_PROJ, 256, 256, 8, 8 };
  tab.d[8]  = { cg_w2a,    WT_W2A,  256, 64, 2, 8 };
  tab.d[9]  = { cg_w2m,    WT_W2M,  256, 64, 2, 8 };
  tab.d[10] = { cg_wf,     WT_WF,   256, 512, 16, 8 };
  tab.d[11] = { mlp_w1,    WT_MLP1,1024, 256, 8, 32 };
  tab.d[12] = { mlp_w2,    WT_MLP2, 256,1024, 32, 8 };
  tab.d[13] = { cg_w1a,    WT_W1A,   64, 256, 8, 2 };
  tab.d[14] = { cg_w1m,    WT_W1M,   64, 256, 8, 2 };
  int ntiles = 0;
  for (int i=0;i<15;i++) ntiles += tab.d[i].kb * tab.d[i].nt;
  wtall_k<<<ntiles,256,0,stream>>>(tab);

  // Phase A
  ln2x_k<<<8192,256,0,stream>>>(x, ln1_w, ln1_b, ns_w, ns_b, XN, XNS);
  gemm_k<EPI_NONE,float,float><<<dim3(1,512),256,0,stream>>>(XNS,nullptr,256,0, m_win+1152,1160, nullptr, nullptr, DTRAW, 32768,8);
  acs_k<<<256,256,0,stream>>>(DTRAW, m_dt_b, m_a_log, DT, ACS);

  // Phases B..F per chunk of NB batches
  for (int cc=0; cc<NC; cc++){
    int cb0 = cc*NB;
    const u16* XNSc = XNS + (size_t)cb0*TB;
    const float* DTcp = DT + (size_t)cb0*32768;
    const float* ACScp = ACS + (size_t)cb0*32768;
    xbcconv_k<<<dim3(5,NB*64),256,0,stream>>>(XNSc, WT_XBC, m_conv_w, m_conv_b, XCc, XTc);
    states_k<<<NB*128,256,0,stream>>>(XCc, XTc, DTcp, ACScp, STc);
    scan_k<<<NB*32,256,0,stream>>>(STc, ACScp, STINc);
    ydy_k<<<NB*128,256,0,stream>>>(XCc, XTc, DTcp, ACScp, STINc, m_d, Yc);
    mgemm_k<128,128,EPI_NONE,false,false,float,u16><<<dim3(4,NB*32),256,0,stream>>>(XNSc,nullptr,256,0, WT_Z, nullptr, nullptr, Zc, 512, 0);
    urms_k<<<NB*1024,256,0,stream>>>(Yc, Zc, m_norm_w);
    mgemm_k<64,128,EPI_ADD,false,false,u16,u16><<<dim3(2,NB*64),256,0,stream>>>(Yc,nullptr,512,0, WT_WOUT, nullptr, XN + (size_t)cb0*TB, SP + (size_t)cb0*TB, 256, 0);
  }

  // Phase G: tmix (BM=64 for occupancy)
  mgemm_k<64,128,EPI_SILU,false,false,float,u16><<<dim3(2,256),256,0,stream>>>(SP, SP+H2, 256,256, WT_TM1, tm_b1, nullptr, TBUF, 256, 0);
  mgemm_k<64,128,EPI_ADD,false,false,u16,u16><<<dim3(2,256),256,0,stream>>>(TBUF,nullptr,256,0, WT_TM2, tm_b2, SP, XM, 256, 0);
  ln_k<u16><<<4096,256,0,stream>>>(XM, nt_w, nt_b, XM);
  mgemm_k<64,128,EPI_SILU,false,false,float,u16><<<dim3(2,256),256,0,stream>>>(SP+H2, XM, 256,256, WT_TM1, tm_b1, nullptr, TBUF, 256, 0);
  mgemm_k<64,128,EPI_ADD,false,false,u16,u16><<<dim3(2,256),256,0,stream>>>(TBUF,nullptr,256,0, WT_TM2, tm_b2, SP+H2, XM+H2, 256, 0);
  ln_k<u16><<<4096,256,0,stream>>>(XM+H2, nt_w, nt_b, XM+H2);

  // Phase H: window attention
  for (int cc=0; cc<NC; cc++){
    int r0 = cc*NB*4096;
    mgemm_k<128,128,EPI_NONE,true,false,float,u16><<<dim3(6,NB*32),256,0,stream>>>(XN,nullptr,256,0, WT_QKV, qkv_b, nullptr, QKVc, 768, r0);
    attn_k<<<dim3(NB*64,8),256,0,stream>>>(QKVc, rpb, OWc);
    mgemm_k<64,128,EPI_SIGMUL,true,false,u16,u16><<<dim3(2,NB*64),256,0,stream>>>(XN,nullptr,256,0, WT_GATE, gate_b, OWc, OWc, 256, r0);
    mgemm_k<64,128,EPI_NONE,false,true,float,u16><<<dim3(2,NB*64),256,0,stream>>>(OWc,nullptr,256,0, WT_PROJ, proj_b, nullptr, XA, 256, r0);
  }

  // Phase I: cross gates (BM=64 where N=256)
  mgemm_k<128,64,EPI_RELU,false,false,float,u16><<<dim3(1,256),256,0,stream>>>(XA,nullptr,256,0, WT_W1A, cg_b1a, nullptr, CGHA, 64, 0);
  mgemm_k<128,64,EPI_RELU,false,false,float,u16><<<dim3(1,256),256,0,stream>>>(XM,nullptr,256,0, WT_W1M, cg_b1m, nullptr, CGHM, 64, 0);
  mgemm_k<64,128,EPI_SIGMUL,false,false,u16,u16><<<dim3(2,512),256,0,stream>>>(CGHA,nullptr,64,0, WT_W2A, cg_b2a, XM, XM, 256, 0);
  mgemm_k<64,128,EPI_SIGMUL,false,false,u16,u16><<<dim3(2,512),256,0,stream>>>(CGHM,nullptr,64,0, WT_W2M, cg_b2m, XA, XA, 256, 0);
  mgemm_k<64,128,EPI_ADD,false,false,float,float><<<dim3(2,512),256,0,stream>>>(XM, XA, 256,256, WT_WF, cg_bf, x, dout, 256, 0);

  // Phase J: MLP (MLP2 at BM=64)
  for (int q=0; q<32768/RJ; q++){
    float* XOq = dout + (size_t)q*RJ*256;
    ln_k<float><<<RJ/4,256,0,stream>>>(XOq, ln2_w, ln2_b, LNc);
    mgemm_k<128,128,EPI_GELU,false,false,float,u16><<<dim3(8,RJ/128),256,0,stream>>>(LNc,nullptr,256,0, WT_MLP1, mlp_b1, nullptr, MHc, 1024, 0);
    mgemm_k<64,128,EPI_ADD,false,false,float,float><<<dim3(2,RJ/64),256,0,stream>>>(MHc,nullptr,1024,0, WT_MLP2, mlp_b2, XOq, XOq, 256, 0);
  }
}